// Round 4
// baseline (2420.738 us; speedup 1.0000x reference)
//
#include <hip/hip_runtime.h>
#include <hip/hip_bf16.h>

constexpr int F = 128, H1 = 64, H2 = 32, K11 = 3;
constexpr int SB = 6;               // 64 rows per scatter bucket

// ---- bf16 helpers (bf16 -> f32 is a shift; f32 -> bf16 is RNE bit-trick) ----
static __device__ __forceinline__ float bf_lo(unsigned u) { return __uint_as_float(u << 16); }
static __device__ __forceinline__ float bf_hi(unsigned u) { return __uint_as_float(u & 0xffff0000u); }
static __device__ __forceinline__ unsigned pack_bf16(float a, float b) {
    unsigned ua = __float_as_uint(a), ub = __float_as_uint(b);
    unsigned ra = (ua + 0x7fffu + ((ua >> 16) & 1u)) >> 16;
    unsigned rb = (ub + 0x7fffu + ((ub >> 16) & 1u)) & 0xffff0000u;
    return ra | rb;
}

// ---------------- dense GEMM: C[M x HH](bf16) = A[M x FF] @ W[FF x HH] ----------------
template<int FF, int HH, int TPR, bool BATCH, bool ABF16>
__launch_bounds__(256)
__global__ void gemm_kernel(const void* __restrict__ Av, const float* __restrict__ W,
                            ushort* __restrict__ C, int M) {
    if (BATCH) {
        W += (size_t)blockIdx.y * FF * HH;
        C += (size_t)blockIdx.y * (size_t)M * HH;
    }
    __shared__ float Ws[FF * HH];
    const int tid = threadIdx.x;
    for (int i = tid * 4; i < FF * HH; i += 1024)
        *reinterpret_cast<float4*>(&Ws[i]) = *reinterpret_cast<const float4*>(&W[i]);
    __syncthreads();

    constexpr int CPT = HH / TPR;
    const int t = blockIdx.x * 256 + tid;
    const int row = t / TPR;
    const int sub = t % TPR;
    if (row >= M) return;

    float acc[CPT];
#pragma unroll
    for (int j = 0; j < CPT; ++j) acc[j] = 0.f;

    for (int k = 0; k < FF; k += 8) {
        float av[8];
        if (ABF16) {
            const ushort* A = (const ushort*)Av;
            const uint4 u = *reinterpret_cast<const uint4*>(&A[(size_t)row * FF + k]);
            av[0] = bf_lo(u.x); av[1] = bf_hi(u.x);
            av[2] = bf_lo(u.y); av[3] = bf_hi(u.y);
            av[4] = bf_lo(u.z); av[5] = bf_hi(u.z);
            av[6] = bf_lo(u.w); av[7] = bf_hi(u.w);
        } else {
            const float* A = (const float*)Av;
            const float4 u0 = *reinterpret_cast<const float4*>(&A[(size_t)row * FF + k]);
            const float4 u1 = *reinterpret_cast<const float4*>(&A[(size_t)row * FF + k + 4]);
            av[0] = u0.x; av[1] = u0.y; av[2] = u0.z; av[3] = u0.w;
            av[4] = u1.x; av[5] = u1.y; av[6] = u1.z; av[7] = u1.w;
        }
#pragma unroll
        for (int kk = 0; kk < 8; ++kk) {
            const float* wr = &Ws[(k + kk) * HH + sub * CPT];
#pragma unroll
            for (int j = 0; j < CPT; j += 4) {
                const float4 wv = *reinterpret_cast<const float4*>(&wr[j]);
                acc[j + 0] = fmaf(av[kk], wv.x, acc[j + 0]);
                acc[j + 1] = fmaf(av[kk], wv.y, acc[j + 1]);
                acc[j + 2] = fmaf(av[kk], wv.z, acc[j + 2]);
                acc[j + 3] = fmaf(av[kk], wv.w, acc[j + 3]);
            }
        }
    }
    unsigned packed[CPT / 2];
#pragma unroll
    for (int j = 0; j < CPT; j += 2) packed[j / 2] = pack_bf16(acc[j], acc[j + 1]);
    unsigned* c = (unsigned*)(C + (size_t)row * HH + sub * CPT);
#pragma unroll
    for (int j = 0; j < CPT / 2; j += 4)
        *reinterpret_cast<uint4*>(&c[j]) = make_uint4(packed[j], packed[j + 1], packed[j + 2], packed[j + 3]);
}

// ---------------- CSR build ----------------
__global__ void hist_kernel(const int* __restrict__ rows, int E, int* __restrict__ cnt) {
    int e = blockIdx.x * blockDim.x + threadIdx.x;
    if (e < E) atomicAdd(&cnt[rows[e]], 1);
}

__launch_bounds__(256)
__global__ void scan1_kernel(const int* __restrict__ cnt, int* __restrict__ bsums) {
    __shared__ int lds[256];
    const int tid = threadIdx.x;
    const int4 v = *reinterpret_cast<const int4*>(&cnt[blockIdx.x * 1024 + tid * 4]);
    lds[tid] = v.x + v.y + v.z + v.w;
    __syncthreads();
    for (int off = 128; off > 0; off >>= 1) {
        if (tid < off) lds[tid] += lds[tid + off];
        __syncthreads();
    }
    if (tid == 0) bsums[blockIdx.x] = lds[0];
}

__launch_bounds__(256)
__global__ void scan2_kernel(const int* __restrict__ bsums, int* __restrict__ bofs, int nb) {
    __shared__ int lds[256];
    const int t = threadIdx.x;
    const int v = (t < nb) ? bsums[t] : 0;
    lds[t] = v;
    __syncthreads();
    for (int off = 1; off < 256; off <<= 1) {
        int a = (t >= off) ? lds[t - off] : 0;
        __syncthreads();
        lds[t] += a;
        __syncthreads();
    }
    if (t < nb) bofs[t] = lds[t] - v;
}

__launch_bounds__(256)
__global__ void scan3_kernel(const int* __restrict__ cnt, const int* __restrict__ bofs,
                             int* __restrict__ ptr, int* __restrict__ cur) {
    __shared__ int lds[256];
    const int tid = threadIdx.x;
    const int i = blockIdx.x * 1024 + tid * 4;
    const int4 v = *reinterpret_cast<const int4*>(&cnt[i]);
    const int s = v.x + v.y + v.z + v.w;
    lds[tid] = s;
    __syncthreads();
    for (int off = 1; off < 256; off <<= 1) {
        int a = (tid >= off) ? lds[tid - off] : 0;
        __syncthreads();
        lds[tid] += a;
        __syncthreads();
    }
    const int excl = bofs[blockIdx.x] + lds[tid] - s;
    int4 p;
    p.x = excl; p.y = p.x + v.x; p.z = p.y + v.y; p.w = p.z + v.z;
    *reinterpret_cast<int4*>(&ptr[i]) = p;
    *reinterpret_cast<int4*>(&cur[i]) = p;
}

// bucketed scatter, pass 1: edges -> bucket-ordered tmp (seq writes per bucket)
__global__ void bscat1_kernel(const int* __restrict__ rows, const int* __restrict__ cols,
                              const float* __restrict__ vals, int E,
                              int* __restrict__ bcur, uint2* __restrict__ tmp) {
    int e = blockIdx.x * blockDim.x + threadIdx.x;
    if (e >= E) return;
    const unsigned r = (unsigned)rows[e];
    const int pos = atomicAdd(&bcur[r >> SB], 1);
    tmp[pos] = make_uint2((r << 16) | (unsigned)cols[e], __float_as_uint(vals[e]));
}

// pass 2: per bucket (block), tmp -> exact row position in cv (dest span ~16KB, L2-hot)
__global__ void bscat2_kernel(const int* __restrict__ gptr_s, int n, const uint2* __restrict__ tmp,
                              int* __restrict__ cur_s, int2* __restrict__ cv) {
    const int r0 = blockIdx.x << SB;
    const int base = gptr_s[0];
    const int r1 = min(n, r0 + (1 << SB));
    const int lstart = gptr_s[r0] - base;
    const int lend = gptr_s[r1] - base;
    for (int i = lstart + (int)threadIdx.x; i < lend; i += 256) {
        const uint2 t = tmp[i];
        const int pos = atomicAdd(&cur_s[t.x >> 16], 1);
        cv[pos] = make_int2((int)(t.x & 0xffffu), (int)t.y);
    }
}

struct InitArgs { int boff[7]; int s[6]; int n[6]; };
__global__ void bcur_init_kernel(InitArgs a, const int* __restrict__ gptr,
                                 int* __restrict__ bcur, int total) {
    int i = blockIdx.x * 256 + threadIdx.x;
    if (i >= total) return;
    int ai = 0;
    while (ai < 5 && i >= a.boff[ai + 1]) ++ai;
    const int b = i - a.boff[ai];
    const int* gp = gptr + a.s[ai];
    bcur[i] = gp[min(b << SB, a.n[ai])] - gp[0];
}

// single-pass scatter fallback (if rows/cols don't fit 16-bit packing)
__global__ void scatter_kernel(const int* __restrict__ rows, const int* __restrict__ cols,
                               const float* __restrict__ vals, int E,
                               int* __restrict__ cur, int2* __restrict__ cv) {
    int e = blockIdx.x * blockDim.x + threadIdx.x;
    if (e < E) {
        const int pos = atomicAdd(&cur[rows[e]], 1);
        cv[pos] = make_int2(cols[e], __float_as_int(vals[e]));
    }
}

// ---------------- multi-segment CSR SpMM (bf16 X), fused add + optional relu ----------------
struct Segs { int off[4]; const ushort* X[4]; int n; };

template<int HH, bool RELU, bool YF32>
__launch_bounds__(256)
__global__ void spmm_seg_kernel(const int* __restrict__ gptr, const Segs segs,
                                const int2* __restrict__ cv, void* __restrict__ Yv, int nrows) {
    constexpr int LPR = HH / 2;
    constexpr int RPB = 256 / LPR;
    const int row = blockIdx.x * RPB + (int)threadIdx.x / LPR;
    const int lane = (int)threadIdx.x % LPR;
    if (row >= nrows) return;
    float a0 = 0.f, b0 = 0.f, a1 = 0.f, b1 = 0.f, a2 = 0.f, b2 = 0.f, a3 = 0.f, b3 = 0.f;
    for (int sg = 0; sg < segs.n; ++sg) {
        const int* p = gptr + segs.off[sg] + row;
        int i = p[0];
        const int e = p[1];
        const unsigned* X = (const unsigned*)segs.X[sg];
        for (; i + 3 < e; i += 4) {
            const int2 c0 = cv[i], c1 = cv[i + 1], c2 = cv[i + 2], c3 = cv[i + 3];
            const unsigned x0 = X[(size_t)c0.x * LPR + lane];
            const unsigned x1 = X[(size_t)c1.x * LPR + lane];
            const unsigned x2 = X[(size_t)c2.x * LPR + lane];
            const unsigned x3 = X[(size_t)c3.x * LPR + lane];
            const float v0 = __int_as_float(c0.y), v1 = __int_as_float(c1.y);
            const float v2 = __int_as_float(c2.y), v3 = __int_as_float(c3.y);
            a0 = fmaf(v0, bf_lo(x0), a0); b0 = fmaf(v0, bf_hi(x0), b0);
            a1 = fmaf(v1, bf_lo(x1), a1); b1 = fmaf(v1, bf_hi(x1), b1);
            a2 = fmaf(v2, bf_lo(x2), a2); b2 = fmaf(v2, bf_hi(x2), b2);
            a3 = fmaf(v3, bf_lo(x3), a3); b3 = fmaf(v3, bf_hi(x3), b3);
        }
        for (; i < e; ++i) {
            const int2 c = cv[i];
            const unsigned x = X[(size_t)c.x * LPR + lane];
            const float v = __int_as_float(c.y);
            a0 = fmaf(v, bf_lo(x), a0); b0 = fmaf(v, bf_hi(x), b0);
        }
    }
    float r0 = (a0 + a1) + (a2 + a3);
    float r1 = (b0 + b1) + (b2 + b3);
    if (RELU) { r0 = fmaxf(r0, 0.f); r1 = fmaxf(r1, 0.f); }
    if (YF32) {
        *reinterpret_cast<float2*>((float*)Yv + (size_t)row * HH + lane * 2) = make_float2(r0, r1);
    } else {
        ((unsigned*)Yv)[(size_t)row * LPR + lane] = pack_bf16(r0, r1);
    }
}

extern "C" void kernel_launch(void* const* d_in, const int* in_sizes, int n_in,
                              void* d_out, int out_size, void* d_ws, size_t ws_size,
                              hipStream_t stream) {
    const float* feat0 = (const float*)d_in[0];
    const float* feat1 = (const float*)d_in[1];
    const int*   e00_row = (const int*)d_in[2];
    const int*   e00_col = (const int*)d_in[3];
    const float* e00_val = (const float*)d_in[4];
    const int*   e01_row = (const int*)d_in[5];
    const int*   e01_col = (const int*)d_in[6];
    const float* e01_val = (const float*)d_in[7];
    const int*   e10_row = (const int*)d_in[8];
    const int*   e10_col = (const int*)d_in[9];
    const float* e10_val = (const float*)d_in[10];
    const int*   e11_row = (const int*)d_in[11];
    const int*   e11_col = (const int*)d_in[12];
    const float* e11_val = (const float*)d_in[13];
    const float* W1_00 = (const float*)d_in[14];
    const float* W1_01 = (const float*)d_in[15];
    const float* W1_10 = (const float*)d_in[16];
    const float* W1_11 = (const float*)d_in[17];
    const float* W2_00 = (const float*)d_in[18];
    const float* W2_01 = (const float*)d_in[19];
    const float* W2_10 = (const float*)d_in[20];
    const float* W2_11 = (const float*)d_in[21];

    const int N0  = in_sizes[0] / F;
    const int N1  = in_sizes[1] / F;
    const int E00 = in_sizes[2];
    const int E01 = in_sizes[5];
    const int E10 = in_sizes[8];
    const int E11 = in_sizes[11] / K11;
    const long long E_total = (long long)E00 + E01 + E10 + (long long)K11 * E11;

    // count-array concatenation offsets
    const int s00 = 0, s01 = N0, s10 = 2 * N0, s11 = 2 * N0 + N1;
    const int L = 2 * N0 + (1 + K11) * N1;
    const int Lcap = ((L + 1 + 1023) / 1024) * 1024;
    const int nb = Lcap / 1024;

    struct HArr { const int* rows; const int* cols; const float* vals; int E; int s; int n; };
    const HArr arrs[6] = {
        {e00_row, e00_col, e00_val, E00, s00, N0},
        {e01_row, e01_col, e01_val, E01, s01, N0},
        {e10_row, e10_col, e10_val, E10, s10, N1},
        {e11_row,            e11_col,            e11_val,            E11, s11,          N1},
        {e11_row + E11,      e11_col + E11,      e11_val + E11,      E11, s11 + N1,     N1},
        {e11_row + 2 * E11,  e11_col + 2 * E11,  e11_val + 2 * E11,  E11, s11 + 2 * N1, N1},
    };

    // ---- workspace layout ----
    ushort* h0 = (ushort*)d_ws;                         // N0*H1 bf16
    ushort* h1 = h0 + (size_t)N0 * H1;                  // N1*H1 bf16
    ushort* g  = h1 + (size_t)N1 * H1;                  // stage scratch (aliased by tmp during build)
    const size_t gElems = ((size_t)N0 + (size_t)K11 * N1) * H1;

    int* iw = (int*)(g + gElems);
    int* counts = iw;
    int* gptr   = counts + Lcap;
    int* cur    = gptr + Lcap;
    int* bsums  = cur + Lcap;
    int* bofs   = bsums + 256;
    int* bcur   = bofs + 256;
    int totalBuckets = 0;
    int nbk[6], boff[7];
    for (int i = 0; i < 6; ++i) { boff[i] = totalBuckets; nbk[i] = (arrs[i].n + 63) >> SB; totalBuckets += nbk[i]; }
    boff[6] = totalBuckets;
    const int bcap = (totalBuckets + 1) & ~1;
    int2* cv = (int2*)(bcur + bcap);

    const size_t required = ((size_t)(N0 + N1) * H1 + gElems) * 2
                          + ((size_t)3 * Lcap + 512 + bcap + 2 * (size_t)E_total) * 4;
    if (ws_size < required) return;   // harness ws is known-larger (round-3 needed more and passed)

    int maxE = E00;
    for (int i = 1; i < 6; ++i) maxE = maxE > arrs[i].E ? maxE : arrs[i].E;
    const bool canPack = (N0 < 65536) && (N1 < 65536) && ((size_t)maxE * 4 <= gElems);

    // -------- CSR build --------
    hipMemsetAsync(counts, 0, (size_t)Lcap * sizeof(int), stream);
    for (int i = 0; i < 6; ++i)
        hist_kernel<<<(arrs[i].E + 255) / 256, 256, 0, stream>>>(arrs[i].rows, arrs[i].E, counts + arrs[i].s);
    scan1_kernel<<<nb, 256, 0, stream>>>(counts, bsums);
    scan2_kernel<<<1, 256, 0, stream>>>(bsums, bofs, nb);
    scan3_kernel<<<nb, 256, 0, stream>>>(counts, bofs, gptr, cur);

    if (canPack) {
        InitArgs ia;
        for (int i = 0; i < 7; ++i) ia.boff[i] = boff[i];
        for (int i = 0; i < 6; ++i) { ia.s[i] = arrs[i].s; ia.n[i] = arrs[i].n; }
        bcur_init_kernel<<<(totalBuckets + 255) / 256, 256, 0, stream>>>(ia, gptr, bcur, totalBuckets);
        uint2* tmp = (uint2*)g;   // g unused until GEMM stage; stream order makes alias safe
        for (int i = 0; i < 6; ++i) {
            bscat1_kernel<<<(arrs[i].E + 255) / 256, 256, 0, stream>>>(
                arrs[i].rows, arrs[i].cols, arrs[i].vals, arrs[i].E, bcur + boff[i], tmp);
            bscat2_kernel<<<nbk[i], 256, 0, stream>>>(
                gptr + arrs[i].s, arrs[i].n, tmp, cur + arrs[i].s, cv);
        }
    } else {
        for (int i = 0; i < 6; ++i)
            scatter_kernel<<<(arrs[i].E + 255) / 256, 256, 0, stream>>>(
                arrs[i].rows, arrs[i].cols, arrs[i].vals, arrs[i].E, cur + arrs[i].s, cv);
    }

    // -------- main sequence --------
    float* z0 = (float*)d_out;
    float* z1 = (float*)d_out + (size_t)N0 * H2;

    // stage h0 = relu(e00 @ (feat0 W1_00) + e01 @ (feat1 W1_01))
    {
        ushort* gA = g;
        ushort* gB = g + (size_t)N0 * H1;
        gemm_kernel<F, H1, 4, false, false><<<(N0 * 4 + 255) / 256, 256, 0, stream>>>(feat0, W1_00, gA, N0);
        gemm_kernel<F, H1, 4, false, false><<<(N1 * 4 + 255) / 256, 256, 0, stream>>>(feat1, W1_01, gB, N1);
        Segs sg; sg.n = 2;
        sg.off[0] = s00; sg.X[0] = gA;
        sg.off[1] = s01; sg.X[1] = gB;
        spmm_seg_kernel<H1, true, false><<<(N0 + 7) / 8, 256, 0, stream>>>(gptr, sg, cv, h0, N0);
    }
    // stage h1 = relu(e10 @ (feat0 W1_10) + sum_k e11_k @ (feat1 W1_11k))
    {
        ushort* gA = g;
        ushort* gB = g + (size_t)N0 * H1;
        gemm_kernel<F, H1, 4, false, false><<<(N0 * 4 + 255) / 256, 256, 0, stream>>>(feat0, W1_10, gA, N0);
        gemm_kernel<F, H1, 4, true, false><<<dim3((N1 * 4 + 255) / 256, K11), 256, 0, stream>>>(feat1, W1_11, gB, N1);
        Segs sg; sg.n = 4;
        sg.off[0] = s10; sg.X[0] = gA;
        for (int k = 0; k < K11; ++k) { sg.off[1 + k] = s11 + k * N1; sg.X[1 + k] = gB + (size_t)k * N1 * H1; }
        spmm_seg_kernel<H1, true, false><<<(N1 + 7) / 8, 256, 0, stream>>>(gptr, sg, cv, h1, N1);
    }
    // stage z0 = e00 @ (h0 W2_00) + e01 @ (h1 W2_01)
    {
        ushort* gA = g;
        ushort* gB = g + (size_t)N0 * H2;
        gemm_kernel<H1, H2, 4, false, true><<<(N0 * 4 + 255) / 256, 256, 0, stream>>>(h0, W2_00, gA, N0);
        gemm_kernel<H1, H2, 4, false, true><<<(N1 * 4 + 255) / 256, 256, 0, stream>>>(h1, W2_01, gB, N1);
        Segs sg; sg.n = 2;
        sg.off[0] = s00; sg.X[0] = gA;
        sg.off[1] = s01; sg.X[1] = gB;
        spmm_seg_kernel<H2, false, true><<<(N0 + 15) / 16, 256, 0, stream>>>(gptr, sg, cv, z0, N0);
    }
    // stage z1 = e10 @ (h0 W2_10) + sum_k e11_k @ (h1 W2_11k)
    {
        ushort* gA = g;
        ushort* gB = g + (size_t)N0 * H2;
        gemm_kernel<H1, H2, 4, false, true><<<(N0 * 4 + 255) / 256, 256, 0, stream>>>(h0, W2_10, gA, N0);
        gemm_kernel<H1, H2, 4, true, true><<<dim3((N1 * 4 + 255) / 256, K11), 256, 0, stream>>>(h1, W2_11, gB, N1);
        Segs sg; sg.n = 4;
        sg.off[0] = s10; sg.X[0] = gA;
        for (int k = 0; k < K11; ++k) { sg.off[1 + k] = s11 + k * N1; sg.X[1 + k] = gB + (size_t)k * N1 * H2; }
        spmm_seg_kernel<H2, false, true><<<(N1 + 15) / 16, 256, 0, stream>>>(gptr, sg, cv, z1, N1);
    }

    (void)n_in; (void)out_size;
}

// Round 5
// 905.860 us; speedup vs baseline: 2.6723x; 2.6723x over previous
//
#include <hip/hip_runtime.h>
#include <hip/hip_bf16.h>

constexpr int F = 128, H1 = 64, H2 = 32, K11 = 3;

// ---- bf16 helpers (bf16 -> f32 is a shift; f32 -> bf16 is RNE bit-trick) ----
static __device__ __forceinline__ float bf_lo(unsigned u) { return __uint_as_float(u << 16); }
static __device__ __forceinline__ float bf_hi(unsigned u) { return __uint_as_float(u & 0xffff0000u); }
static __device__ __forceinline__ unsigned pack_bf16(float a, float b) {
    unsigned ua = __float_as_uint(a), ub = __float_as_uint(b);
    unsigned ra = (ua + 0x7fffu + ((ua >> 16) & 1u)) >> 16;
    unsigned rb = (ub + 0x7fffu + ((ub >> 16) & 1u)) & 0xffff0000u;
    return ra | rb;
}

// ---------------- dense GEMM: C[M x HH](bf16) = A[M x FF] @ W[FF x HH] ----------------
template<int FF, int HH, int TPR, bool BATCH, bool ABF16>
__launch_bounds__(256)
__global__ void gemm_kernel(const void* __restrict__ Av, const float* __restrict__ W,
                            ushort* __restrict__ C, int M) {
    if (BATCH) {
        W += (size_t)blockIdx.y * FF * HH;
        C += (size_t)blockIdx.y * (size_t)M * HH;
    }
    __shared__ float Ws[FF * HH];
    const int tid = threadIdx.x;
    for (int i = tid * 4; i < FF * HH; i += 1024)
        *reinterpret_cast<float4*>(&Ws[i]) = *reinterpret_cast<const float4*>(&W[i]);
    __syncthreads();

    constexpr int CPT = HH / TPR;
    const int t = blockIdx.x * 256 + tid;
    const int row = t / TPR;
    const int sub = t % TPR;
    if (row >= M) return;

    float acc[CPT];
#pragma unroll
    for (int j = 0; j < CPT; ++j) acc[j] = 0.f;

    for (int k = 0; k < FF; k += 8) {
        float av[8];
        if (ABF16) {
            const ushort* A = (const ushort*)Av;
            const uint4 u = *reinterpret_cast<const uint4*>(&A[(size_t)row * FF + k]);
            av[0] = bf_lo(u.x); av[1] = bf_hi(u.x);
            av[2] = bf_lo(u.y); av[3] = bf_hi(u.y);
            av[4] = bf_lo(u.z); av[5] = bf_hi(u.z);
            av[6] = bf_lo(u.w); av[7] = bf_hi(u.w);
        } else {
            const float* A = (const float*)Av;
            const float4 u0 = *reinterpret_cast<const float4*>(&A[(size_t)row * FF + k]);
            const float4 u1 = *reinterpret_cast<const float4*>(&A[(size_t)row * FF + k + 4]);
            av[0] = u0.x; av[1] = u0.y; av[2] = u0.z; av[3] = u0.w;
            av[4] = u1.x; av[5] = u1.y; av[6] = u1.z; av[7] = u1.w;
        }
#pragma unroll
        for (int kk = 0; kk < 8; ++kk) {
            const float* wr = &Ws[(k + kk) * HH + sub * CPT];
#pragma unroll
            for (int j = 0; j < CPT; j += 4) {
                const float4 wv = *reinterpret_cast<const float4*>(&wr[j]);
                acc[j + 0] = fmaf(av[kk], wv.x, acc[j + 0]);
                acc[j + 1] = fmaf(av[kk], wv.y, acc[j + 1]);
                acc[j + 2] = fmaf(av[kk], wv.z, acc[j + 2]);
                acc[j + 3] = fmaf(av[kk], wv.w, acc[j + 3]);
            }
        }
    }
    unsigned packed[CPT / 2];
#pragma unroll
    for (int j = 0; j < CPT; j += 2) packed[j / 2] = pack_bf16(acc[j], acc[j + 1]);
    unsigned* c = (unsigned*)(C + (size_t)row * HH + sub * CPT);
#pragma unroll
    for (int j = 0; j < CPT / 2; j += 4)
        *reinterpret_cast<uint4*>(&c[j]) = make_uint4(packed[j], packed[j + 1], packed[j + 2], packed[j + 3]);
}

// ---------------- CSR build ----------------
__global__ void hist_kernel(const int* __restrict__ rows, int E, int* __restrict__ cnt) {
    int e = blockIdx.x * blockDim.x + threadIdx.x;
    if (e < E) atomicAdd(&cnt[rows[e]], 1);
}

__launch_bounds__(256)
__global__ void scan1_kernel(const int* __restrict__ cnt, int* __restrict__ bsums) {
    __shared__ int lds[256];
    const int tid = threadIdx.x;
    const int4 v = *reinterpret_cast<const int4*>(&cnt[blockIdx.x * 1024 + tid * 4]);
    lds[tid] = v.x + v.y + v.z + v.w;
    __syncthreads();
    for (int off = 128; off > 0; off >>= 1) {
        if (tid < off) lds[tid] += lds[tid + off];
        __syncthreads();
    }
    if (tid == 0) bsums[blockIdx.x] = lds[0];
}

__launch_bounds__(256)
__global__ void scan2_kernel(const int* __restrict__ bsums, int* __restrict__ bofs, int nb) {
    __shared__ int lds[256];
    const int t = threadIdx.x;
    const int v = (t < nb) ? bsums[t] : 0;
    lds[t] = v;
    __syncthreads();
    for (int off = 1; off < 256; off <<= 1) {
        int a = (t >= off) ? lds[t - off] : 0;
        __syncthreads();
        lds[t] += a;
        __syncthreads();
    }
    if (t < nb) bofs[t] = lds[t] - v;
}

__launch_bounds__(256)
__global__ void scan3_kernel(const int* __restrict__ cnt, const int* __restrict__ bofs,
                             int* __restrict__ ptr, int* __restrict__ cur) {
    __shared__ int lds[256];
    const int tid = threadIdx.x;
    const int i = blockIdx.x * 1024 + tid * 4;
    const int4 v = *reinterpret_cast<const int4*>(&cnt[i]);
    const int s = v.x + v.y + v.z + v.w;
    lds[tid] = s;
    __syncthreads();
    for (int off = 1; off < 256; off <<= 1) {
        int a = (tid >= off) ? lds[tid - off] : 0;
        __syncthreads();
        lds[tid] += a;
        __syncthreads();
    }
    const int excl = bofs[blockIdx.x] + lds[tid] - s;
    int4 p;
    p.x = excl; p.y = p.x + v.x; p.z = p.y + v.y; p.w = p.z + v.z;
    *reinterpret_cast<int4*>(&ptr[i]) = p;
    *reinterpret_cast<int4*>(&cur[i]) = p;
}

// single-pass per-row scatter (round-3 proven: ~at the random-8B-write floor)
__global__ void scatter_kernel(const int* __restrict__ rows, const int* __restrict__ cols,
                               const float* __restrict__ vals, int E,
                               int* __restrict__ cur, int2* __restrict__ cv) {
    int e = blockIdx.x * blockDim.x + threadIdx.x;
    if (e < E) {
        const int pos = atomicAdd(&cur[rows[e]], 1);
        cv[pos] = make_int2(cols[e], __float_as_int(vals[e]));
    }
}
// e11: blockIdx.y = relation k
__global__ void scatter_k_kernel(const int* __restrict__ rows, const int* __restrict__ cols,
                                 const float* __restrict__ vals, int E, int N,
                                 int* __restrict__ cur, int2* __restrict__ cv) {
    int e = blockIdx.x * blockDim.x + threadIdx.x;
    const int k = blockIdx.y;
    if (e < E) {
        const size_t ke = (size_t)k * E + e;
        const int pos = atomicAdd(&cur[(size_t)k * N + rows[ke]], 1);
        cv[pos] = make_int2(cols[ke], __float_as_int(vals[ke]));
    }
}
__global__ void hist_k_kernel(const int* __restrict__ rows, int E, int N, int* __restrict__ cnt) {
    int e = blockIdx.x * blockDim.x + threadIdx.x;
    const int k = blockIdx.y;
    if (e < E) atomicAdd(&cnt[(size_t)k * N + rows[(size_t)k * E + e]], 1);
}

// ---------------- multi-segment CSR SpMM (bf16 X), fused add + optional relu ----------------
struct Segs { int off[4]; const ushort* X[4]; int n; };

template<int HH, bool RELU, bool YF32>
__launch_bounds__(256)
__global__ void spmm_seg_kernel(const int* __restrict__ gptr, const Segs segs,
                                const int2* __restrict__ cv, void* __restrict__ Yv, int nrows) {
    constexpr int LPR = HH / 2;
    constexpr int RPB = 256 / LPR;
    const int row = blockIdx.x * RPB + (int)threadIdx.x / LPR;
    const int lane = (int)threadIdx.x % LPR;
    if (row >= nrows) return;
    float a0 = 0.f, b0 = 0.f, a1 = 0.f, b1 = 0.f, a2 = 0.f, b2 = 0.f, a3 = 0.f, b3 = 0.f;
    for (int sg = 0; sg < segs.n; ++sg) {
        const int* p = gptr + segs.off[sg] + row;
        int i = p[0];
        const int e = p[1];
        const unsigned* X = (const unsigned*)segs.X[sg];
        for (; i + 3 < e; i += 4) {
            const int2 c0 = cv[i], c1 = cv[i + 1], c2 = cv[i + 2], c3 = cv[i + 3];
            const unsigned x0 = X[(size_t)c0.x * LPR + lane];
            const unsigned x1 = X[(size_t)c1.x * LPR + lane];
            const unsigned x2 = X[(size_t)c2.x * LPR + lane];
            const unsigned x3 = X[(size_t)c3.x * LPR + lane];
            const float v0 = __int_as_float(c0.y), v1 = __int_as_float(c1.y);
            const float v2 = __int_as_float(c2.y), v3 = __int_as_float(c3.y);
            a0 = fmaf(v0, bf_lo(x0), a0); b0 = fmaf(v0, bf_hi(x0), b0);
            a1 = fmaf(v1, bf_lo(x1), a1); b1 = fmaf(v1, bf_hi(x1), b1);
            a2 = fmaf(v2, bf_lo(x2), a2); b2 = fmaf(v2, bf_hi(x2), b2);
            a3 = fmaf(v3, bf_lo(x3), a3); b3 = fmaf(v3, bf_hi(x3), b3);
        }
        for (; i < e; ++i) {
            const int2 c = cv[i];
            const unsigned x = X[(size_t)c.x * LPR + lane];
            const float v = __int_as_float(c.y);
            a0 = fmaf(v, bf_lo(x), a0); b0 = fmaf(v, bf_hi(x), b0);
        }
    }
    float r0 = (a0 + a1) + (a2 + a3);
    float r1 = (b0 + b1) + (b2 + b3);
    if (RELU) { r0 = fmaxf(r0, 0.f); r1 = fmaxf(r1, 0.f); }
    if (YF32) {
        *reinterpret_cast<float2*>((float*)Yv + (size_t)row * HH + lane * 2) = make_float2(r0, r1);
    } else {
        ((unsigned*)Yv)[(size_t)row * LPR + lane] = pack_bf16(r0, r1);
    }
}

extern "C" void kernel_launch(void* const* d_in, const int* in_sizes, int n_in,
                              void* d_out, int out_size, void* d_ws, size_t ws_size,
                              hipStream_t stream) {
    const float* feat0 = (const float*)d_in[0];
    const float* feat1 = (const float*)d_in[1];
    const int*   e00_row = (const int*)d_in[2];
    const int*   e00_col = (const int*)d_in[3];
    const float* e00_val = (const float*)d_in[4];
    const int*   e01_row = (const int*)d_in[5];
    const int*   e01_col = (const int*)d_in[6];
    const float* e01_val = (const float*)d_in[7];
    const int*   e10_row = (const int*)d_in[8];
    const int*   e10_col = (const int*)d_in[9];
    const float* e10_val = (const float*)d_in[10];
    const int*   e11_row = (const int*)d_in[11];
    const int*   e11_col = (const int*)d_in[12];
    const float* e11_val = (const float*)d_in[13];
    const float* W1_00 = (const float*)d_in[14];
    const float* W1_01 = (const float*)d_in[15];
    const float* W1_10 = (const float*)d_in[16];
    const float* W1_11 = (const float*)d_in[17];
    const float* W2_00 = (const float*)d_in[18];
    const float* W2_01 = (const float*)d_in[19];
    const float* W2_10 = (const float*)d_in[20];
    const float* W2_11 = (const float*)d_in[21];

    const int N0  = in_sizes[0] / F;
    const int N1  = in_sizes[1] / F;
    const int E00 = in_sizes[2];
    const int E01 = in_sizes[5];
    const int E10 = in_sizes[8];
    const int E11 = in_sizes[11] / K11;
    const long long E_total = (long long)E00 + E01 + E10 + (long long)K11 * E11;

    // count-array concatenation offsets
    const int s00 = 0, s01 = N0, s10 = 2 * N0, s11 = 2 * N0 + N1;
    const int L = 2 * N0 + (1 + K11) * N1;
    const int Lcap = ((L + 1 + 1023) / 1024) * 1024;
    const int nb = Lcap / 1024;

    // ---- workspace layout ----
    ushort* h0 = (ushort*)d_ws;                         // N0*H1 bf16
    ushort* h1 = h0 + (size_t)N0 * H1;                  // N1*H1 bf16
    ushort* g  = h1 + (size_t)N1 * H1;                  // GEMM stage scratch
    const size_t gElems = ((size_t)N0 + (size_t)K11 * N1) * H1;

    int* iw = (int*)(g + gElems);
    int* counts = iw;
    int* gptr   = counts + Lcap;
    int* cur    = gptr + Lcap;
    int* bsums  = cur + Lcap;
    int* bofs   = bsums + 256;
    int2* cv    = (int2*)(bofs + 256);

    const size_t required = ((size_t)(N0 + N1) * H1 + gElems) * 2
                          + ((size_t)3 * Lcap + 512 + 2 * (size_t)E_total) * 4;
    if (ws_size < required) return;

    // -------- CSR build --------
    hipMemsetAsync(counts, 0, (size_t)Lcap * sizeof(int), stream);
    hist_kernel<<<(E00 + 255) / 256, 256, 0, stream>>>(e00_row, E00, counts + s00);
    hist_kernel<<<(E01 + 255) / 256, 256, 0, stream>>>(e01_row, E01, counts + s01);
    hist_kernel<<<(E10 + 255) / 256, 256, 0, stream>>>(e10_row, E10, counts + s10);
    hist_k_kernel<<<dim3((E11 + 255) / 256, K11), 256, 0, stream>>>(e11_row, E11, N1, counts + s11);

    scan1_kernel<<<nb, 256, 0, stream>>>(counts, bsums);
    scan2_kernel<<<1, 256, 0, stream>>>(bsums, bofs, nb);
    scan3_kernel<<<nb, 256, 0, stream>>>(counts, bofs, gptr, cur);

    scatter_kernel<<<(E00 + 255) / 256, 256, 0, stream>>>(e00_row, e00_col, e00_val, E00, cur + s00, cv);
    scatter_kernel<<<(E01 + 255) / 256, 256, 0, stream>>>(e01_row, e01_col, e01_val, E01, cur + s01, cv);
    scatter_kernel<<<(E10 + 255) / 256, 256, 0, stream>>>(e10_row, e10_col, e10_val, E10, cur + s10, cv);
    scatter_k_kernel<<<dim3((E11 + 255) / 256, K11), 256, 0, stream>>>(e11_row, e11_col, e11_val, E11, N1, cur + s11, cv);

    // -------- main sequence --------
    float* z0 = (float*)d_out;
    float* z1 = (float*)d_out + (size_t)N0 * H2;

    // stage h0 = relu(e00 @ (feat0 W1_00) + e01 @ (feat1 W1_01))
    {
        ushort* gA = g;
        ushort* gB = g + (size_t)N0 * H1;
        gemm_kernel<F, H1, 4, false, false><<<(N0 * 4 + 255) / 256, 256, 0, stream>>>(feat0, W1_00, gA, N0);
        gemm_kernel<F, H1, 4, false, false><<<(N1 * 4 + 255) / 256, 256, 0, stream>>>(feat1, W1_01, gB, N1);
        Segs sg; sg.n = 2;
        sg.off[0] = s00; sg.X[0] = gA;
        sg.off[1] = s01; sg.X[1] = gB;
        spmm_seg_kernel<H1, true, false><<<(N0 + 7) / 8, 256, 0, stream>>>(gptr, sg, cv, h0, N0);
    }
    // stage h1 = relu(e10 @ (feat0 W1_10) + sum_k e11_k @ (feat1 W1_11k))
    {
        ushort* gA = g;
        ushort* gB = g + (size_t)N0 * H1;
        gemm_kernel<F, H1, 4, false, false><<<(N0 * 4 + 255) / 256, 256, 0, stream>>>(feat0, W1_10, gA, N0);
        gemm_kernel<F, H1, 4, true, false><<<dim3((N1 * 4 + 255) / 256, K11), 256, 0, stream>>>(feat1, W1_11, gB, N1);
        Segs sg; sg.n = 4;
        sg.off[0] = s10; sg.X[0] = gA;
        for (int k = 0; k < K11; ++k) { sg.off[1 + k] = s11 + k * N1; sg.X[1 + k] = gB + (size_t)k * N1 * H1; }
        spmm_seg_kernel<H1, true, false><<<(N1 + 7) / 8, 256, 0, stream>>>(gptr, sg, cv, h1, N1);
    }
    // stage z0 = e00 @ (h0 W2_00) + e01 @ (h1 W2_01)
    {
        ushort* gA = g;
        ushort* gB = g + (size_t)N0 * H2;
        gemm_kernel<H1, H2, 4, false, true><<<(N0 * 4 + 255) / 256, 256, 0, stream>>>(h0, W2_00, gA, N0);
        gemm_kernel<H1, H2, 4, false, true><<<(N1 * 4 + 255) / 256, 256, 0, stream>>>(h1, W2_01, gB, N1);
        Segs sg; sg.n = 2;
        sg.off[0] = s00; sg.X[0] = gA;
        sg.off[1] = s01; sg.X[1] = gB;
        spmm_seg_kernel<H2, false, true><<<(N0 + 15) / 16, 256, 0, stream>>>(gptr, sg, cv, z0, N0);
    }
    // stage z1 = e10 @ (h0 W2_10) + sum_k e11_k @ (h1 W2_11k)
    {
        ushort* gA = g;
        ushort* gB = g + (size_t)N0 * H2;
        gemm_kernel<H1, H2, 4, false, true><<<(N0 * 4 + 255) / 256, 256, 0, stream>>>(h0, W2_10, gA, N0);
        gemm_kernel<H1, H2, 4, true, true><<<dim3((N1 * 4 + 255) / 256, K11), 256, 0, stream>>>(h1, W2_11, gB, N1);
        Segs sg; sg.n = 4;
        sg.off[0] = s10; sg.X[0] = gA;
        for (int k = 0; k < K11; ++k) { sg.off[1 + k] = s11 + k * N1; sg.X[1 + k] = gB + (size_t)k * N1 * H2; }
        spmm_seg_kernel<H2, false, true><<<(N1 + 15) / 16, 256, 0, stream>>>(gptr, sg, cv, z1, N1);
    }

    (void)n_in; (void)out_size;
}

// Round 6
// 544.873 us; speedup vs baseline: 4.4428x; 1.6625x over previous
//
#include <hip/hip_runtime.h>
#include <hip/hip_bf16.h>

constexpr int F = 128, H1 = 64, H2 = 32, K11 = 3;
constexpr int BSH = 7;                 // 128 rows per bin

// ---- bf16 helpers ----
static __device__ __forceinline__ float bf_lo(unsigned u) { return __uint_as_float(u << 16); }
static __device__ __forceinline__ float bf_hi(unsigned u) { return __uint_as_float(u & 0xffff0000u); }
static __device__ __forceinline__ unsigned pack_bf16(float a, float b) {
    unsigned ua = __float_as_uint(a), ub = __float_as_uint(b);
    unsigned ra = (ua + 0x7fffu + ((ua >> 16) & 1u)) >> 16;
    unsigned rb = (ub + 0x7fffu + ((ub >> 16) & 1u)) & 0xffff0000u;
    return ra | rb;
}

// ---------------- dense GEMM: C[M x HH](bf16) = A[M x FF] @ W[FF x HH] ----------------
template<int FF, int HH, int TPR, bool BATCH, bool ABF16>
__launch_bounds__(256)
__global__ void gemm_kernel(const void* __restrict__ Av, const float* __restrict__ W,
                            ushort* __restrict__ C, int M) {
    if (BATCH) {
        W += (size_t)blockIdx.y * FF * HH;
        C += (size_t)blockIdx.y * (size_t)M * HH;
    }
    __shared__ float Ws[FF * HH];
    const int tid = threadIdx.x;
    for (int i = tid * 4; i < FF * HH; i += 1024)
        *reinterpret_cast<float4*>(&Ws[i]) = *reinterpret_cast<const float4*>(&W[i]);
    __syncthreads();

    constexpr int CPT = HH / TPR;
    const int t = blockIdx.x * 256 + tid;
    const int row = t / TPR;
    const int sub = t % TPR;
    if (row >= M) return;

    float acc[CPT];
#pragma unroll
    for (int j = 0; j < CPT; ++j) acc[j] = 0.f;

    for (int k = 0; k < FF; k += 8) {
        float av[8];
        if (ABF16) {
            const ushort* A = (const ushort*)Av;
            const uint4 u = *reinterpret_cast<const uint4*>(&A[(size_t)row * FF + k]);
            av[0] = bf_lo(u.x); av[1] = bf_hi(u.x);
            av[2] = bf_lo(u.y); av[3] = bf_hi(u.y);
            av[4] = bf_lo(u.z); av[5] = bf_hi(u.z);
            av[6] = bf_lo(u.w); av[7] = bf_hi(u.w);
        } else {
            const float* A = (const float*)Av;
            const float4 u0 = *reinterpret_cast<const float4*>(&A[(size_t)row * FF + k]);
            const float4 u1 = *reinterpret_cast<const float4*>(&A[(size_t)row * FF + k + 4]);
            av[0] = u0.x; av[1] = u0.y; av[2] = u0.z; av[3] = u0.w;
            av[4] = u1.x; av[5] = u1.y; av[6] = u1.z; av[7] = u1.w;
        }
#pragma unroll
        for (int kk = 0; kk < 8; ++kk) {
            const float* wr = &Ws[(k + kk) * HH + sub * CPT];
#pragma unroll
            for (int j = 0; j < CPT; j += 4) {
                const float4 wv = *reinterpret_cast<const float4*>(&wr[j]);
                acc[j + 0] = fmaf(av[kk], wv.x, acc[j + 0]);
                acc[j + 1] = fmaf(av[kk], wv.y, acc[j + 1]);
                acc[j + 2] = fmaf(av[kk], wv.z, acc[j + 2]);
                acc[j + 3] = fmaf(av[kk], wv.w, acc[j + 3]);
            }
        }
    }
    unsigned packed[CPT / 2];
#pragma unroll
    for (int j = 0; j < CPT; j += 2) packed[j / 2] = pack_bf16(acc[j], acc[j + 1]);
    unsigned* c = (unsigned*)(C + (size_t)row * HH + sub * CPT);
#pragma unroll
    for (int j = 0; j < CPT / 2; j += 4)
        *reinterpret_cast<uint4*>(&c[j]) = make_uint4(packed[j], packed[j + 1], packed[j + 2], packed[j + 3]);
}

// ---------------- NEW CSR build: two-level bin partition ----------------
struct BinDesc { const int* rows[6]; int E[6]; int n[6]; int binBase[6]; };

// A1: per-block LDS histogram of bins -> global bin counts
__launch_bounds__(256)
__global__ void binhist_kernel(BinDesc d, int* __restrict__ binCnt) {
    const int a = blockIdx.y;
    const int E = d.E[a];
    const int start = blockIdx.x * 8192;
    if (start >= E) return;
    const int nb = (d.n[a] + 127) >> BSH;     // <= 512
    __shared__ int h[512];
    for (int i = threadIdx.x; i < nb; i += 256) h[i] = 0;
    __syncthreads();
    const int* rows = d.rows[a];
    const int end = min(E, start + 8192);
    for (int e = start + (int)threadIdx.x; e < end; e += 256)
        atomicAdd(&h[rows[e] >> BSH], 1);
    __syncthreads();
    int* bc = binCnt + d.binBase[a];
    for (int i = threadIdx.x; i < nb; i += 256)
        if (h[i]) atomicAdd(&bc[i], h[i]);
}

// A2: single-block exclusive scan over all bins (TB ~ 1400)
__launch_bounds__(256)
__global__ void binscan_kernel(const int* __restrict__ binCnt, int* __restrict__ binPtr,
                               int* __restrict__ binCur, int TB, int Etot,
                               int* __restrict__ gptr, int Lidx) {
    __shared__ int lds[256];
    __shared__ int carry;
    if (threadIdx.x == 0) carry = 0;
    __syncthreads();
    for (int base = 0; base < TB; base += 256) {
        const int i = base + threadIdx.x;
        const int v = (i < TB) ? binCnt[i] : 0;
        lds[threadIdx.x] = v;
        __syncthreads();
        for (int o = 1; o < 256; o <<= 1) {
            int t = (threadIdx.x >= o) ? lds[threadIdx.x - o] : 0;
            __syncthreads();
            lds[threadIdx.x] += t;
            __syncthreads();
        }
        const int c = carry;
        __syncthreads();
        if (i < TB) {
            const int excl = c + lds[threadIdx.x] - v;
            binPtr[i] = excl;
            binCur[i] = excl;
        }
        if (threadIdx.x == 255) carry = c + lds[255];
        __syncthreads();
    }
    if (threadIdx.x == 0) { binPtr[TB] = Etot; gptr[Lidx] = Etot; }
}

// A3: partition edges into bin-grouped tmp; per-block range reservation per bin.
// binCur passed pre-offset by binBase; tmp indices are array-local (subtract edgeBase).
__launch_bounds__(256)
__global__ void partition_kernel(const int* __restrict__ rows, const int* __restrict__ cols,
                                 const float* __restrict__ vals, int E, int nbins,
                                 int* __restrict__ binCur, int edgeBase,
                                 uint2* __restrict__ tmp) {
    const int start = blockIdx.x * 4096;
    __shared__ int h[512];
    __shared__ int base[512];
    for (int i = threadIdx.x; i < nbins; i += 256) h[i] = 0;
    __syncthreads();
    int r[16];
#pragma unroll
    for (int j = 0; j < 16; ++j) {
        const int idx = start + j * 256 + (int)threadIdx.x;
        r[j] = (idx < E) ? rows[idx] : -1;
        if (r[j] >= 0) atomicAdd(&h[r[j] >> BSH], 1);
    }
    __syncthreads();
    for (int i = threadIdx.x; i < nbins; i += 256) {
        const int c = h[i];
        base[i] = c ? atomicAdd(&binCur[i], c) : 0;
    }
    __syncthreads();
    for (int i = threadIdx.x; i < nbins; i += 256) h[i] = 0;   // reuse as local cursor
    __syncthreads();
#pragma unroll
    for (int j = 0; j < 16; ++j) {
        if (r[j] >= 0) {
            const int idx = start + j * 256 + (int)threadIdx.x;
            const int b = r[j] >> BSH;
            const int p = atomicAdd(&h[b], 1);
            tmp[base[b] + p - edgeBase] =
                make_uint2(((unsigned)(r[j] & 127) << 16) | (unsigned)cols[idx],
                           __float_as_uint(vals[idx]));
        }
    }
}

// B: per bin -> exact row positions in cv + gptr for 128 rows.
// binPtr pre-offset by binBase, gptr pre-offset by array row start.
__launch_bounds__(256)
__global__ void finalize_kernel(const uint2* __restrict__ tmp, const int* __restrict__ binPtr,
                                int edgeBase, int n, int* __restrict__ gptr,
                                int2* __restrict__ cv) {
    const int b = blockIdx.x;
    const int binStart = binPtr[b];
    const int binEnd = binPtr[b + 1];
    const int lo = binStart - edgeBase, hi = binEnd - edgeBase;
    __shared__ int cnt[128];
    __shared__ int off[128];
    __shared__ int cur[128];
    if (threadIdx.x < 128) cnt[threadIdx.x] = 0;
    __syncthreads();
    for (int i = lo + (int)threadIdx.x; i < hi; i += 256)
        atomicAdd(&cnt[tmp[i].x >> 16], 1);
    __syncthreads();
    if (threadIdx.x < 128) off[threadIdx.x] = cnt[threadIdx.x];
    __syncthreads();
    for (int o = 1; o < 128; o <<= 1) {
        int t = 0;
        if (threadIdx.x < 128 && (int)threadIdx.x >= o) t = off[threadIdx.x - o];
        __syncthreads();
        if (threadIdx.x < 128) off[threadIdx.x] += t;
        __syncthreads();
    }
    const int r0 = b << BSH;
    const int nrows = min(128, n - r0);
    if (threadIdx.x < 128) {
        const int excl = off[threadIdx.x] - cnt[threadIdx.x];
        cur[threadIdx.x] = excl;
        if ((int)threadIdx.x < nrows) gptr[r0 + threadIdx.x] = binStart + excl;
    }
    __syncthreads();
    for (int i = lo + (int)threadIdx.x; i < hi; i += 256) {
        const uint2 t = tmp[i];
        const int p = atomicAdd(&cur[t.x >> 16], 1);
        cv[binStart + p] = make_int2((int)(t.x & 0xffffu), (int)t.y);
    }
}

// ---------------- fallback build (round-5 proven) ----------------
__global__ void hist_kernel(const int* __restrict__ rows, int E, int* __restrict__ cnt) {
    int e = blockIdx.x * blockDim.x + threadIdx.x;
    if (e < E) atomicAdd(&cnt[rows[e]], 1);
}
__global__ void hist_k_kernel(const int* __restrict__ rows, int E, int N, int* __restrict__ cnt) {
    int e = blockIdx.x * blockDim.x + threadIdx.x;
    const int k = blockIdx.y;
    if (e < E) atomicAdd(&cnt[(size_t)k * N + rows[(size_t)k * E + e]], 1);
}
__launch_bounds__(256)
__global__ void scan1_kernel(const int* __restrict__ cnt, int* __restrict__ bsums) {
    __shared__ int lds[256];
    const int tid = threadIdx.x;
    const int4 v = *reinterpret_cast<const int4*>(&cnt[blockIdx.x * 1024 + tid * 4]);
    lds[tid] = v.x + v.y + v.z + v.w;
    __syncthreads();
    for (int off = 128; off > 0; off >>= 1) {
        if (tid < off) lds[tid] += lds[tid + off];
        __syncthreads();
    }
    if (tid == 0) bsums[blockIdx.x] = lds[0];
}
__launch_bounds__(256)
__global__ void scan2_kernel(const int* __restrict__ bsums, int* __restrict__ bofs, int nb) {
    __shared__ int lds[256];
    const int t = threadIdx.x;
    const int v = (t < nb) ? bsums[t] : 0;
    lds[t] = v;
    __syncthreads();
    for (int off = 1; off < 256; off <<= 1) {
        int a = (t >= off) ? lds[t - off] : 0;
        __syncthreads();
        lds[t] += a;
        __syncthreads();
    }
    if (t < nb) bofs[t] = lds[t] - v;
}
__launch_bounds__(256)
__global__ void scan3_kernel(const int* __restrict__ cnt, const int* __restrict__ bofs,
                             int* __restrict__ ptr, int* __restrict__ cur) {
    __shared__ int lds[256];
    const int tid = threadIdx.x;
    const int i = blockIdx.x * 1024 + tid * 4;
    const int4 v = *reinterpret_cast<const int4*>(&cnt[i]);
    const int s = v.x + v.y + v.z + v.w;
    lds[tid] = s;
    __syncthreads();
    for (int off = 1; off < 256; off <<= 1) {
        int a = (tid >= off) ? lds[tid - off] : 0;
        __syncthreads();
        lds[tid] += a;
        __syncthreads();
    }
    const int excl = bofs[blockIdx.x] + lds[tid] - s;
    int4 p;
    p.x = excl; p.y = p.x + v.x; p.z = p.y + v.y; p.w = p.z + v.z;
    *reinterpret_cast<int4*>(&ptr[i]) = p;
    *reinterpret_cast<int4*>(&cur[i]) = p;
}
__global__ void scatter_kernel(const int* __restrict__ rows, const int* __restrict__ cols,
                               const float* __restrict__ vals, int E,
                               int* __restrict__ cur, int2* __restrict__ cv) {
    int e = blockIdx.x * blockDim.x + threadIdx.x;
    if (e < E) {
        const int pos = atomicAdd(&cur[rows[e]], 1);
        cv[pos] = make_int2(cols[e], __float_as_int(vals[e]));
    }
}
__global__ void scatter_k_kernel(const int* __restrict__ rows, const int* __restrict__ cols,
                                 const float* __restrict__ vals, int E, int N,
                                 int* __restrict__ cur, int2* __restrict__ cv) {
    int e = blockIdx.x * blockDim.x + threadIdx.x;
    const int k = blockIdx.y;
    if (e < E) {
        const size_t ke = (size_t)k * E + e;
        const int pos = atomicAdd(&cur[(size_t)k * N + rows[ke]], 1);
        cv[pos] = make_int2(cols[ke], __float_as_int(vals[ke]));
    }
}

// ---------------- multi-segment CSR SpMM (bf16 X), fused add + optional relu ----------------
struct Segs { int off[4]; const ushort* X[4]; int n; };

template<int HH, bool RELU, bool YF32>
__launch_bounds__(256)
__global__ void spmm_seg_kernel(const int* __restrict__ gptr, const Segs segs,
                                const int2* __restrict__ cv, void* __restrict__ Yv, int nrows) {
    constexpr int LPR = HH / 2;
    constexpr int RPB = 256 / LPR;
    const int row = blockIdx.x * RPB + (int)threadIdx.x / LPR;
    const int lane = (int)threadIdx.x % LPR;
    if (row >= nrows) return;
    float a0 = 0.f, b0 = 0.f, a1 = 0.f, b1 = 0.f, a2 = 0.f, b2 = 0.f, a3 = 0.f, b3 = 0.f;
    for (int sg = 0; sg < segs.n; ++sg) {
        const int* p = gptr + segs.off[sg] + row;
        int i = p[0];
        const int e = p[1];
        const unsigned* X = (const unsigned*)segs.X[sg];
        for (; i + 3 < e; i += 4) {
            const int2 c0 = cv[i], c1 = cv[i + 1], c2 = cv[i + 2], c3 = cv[i + 3];
            const unsigned x0 = X[(size_t)c0.x * LPR + lane];
            const unsigned x1 = X[(size_t)c1.x * LPR + lane];
            const unsigned x2 = X[(size_t)c2.x * LPR + lane];
            const unsigned x3 = X[(size_t)c3.x * LPR + lane];
            const float v0 = __int_as_float(c0.y), v1 = __int_as_float(c1.y);
            const float v2 = __int_as_float(c2.y), v3 = __int_as_float(c3.y);
            a0 = fmaf(v0, bf_lo(x0), a0); b0 = fmaf(v0, bf_hi(x0), b0);
            a1 = fmaf(v1, bf_lo(x1), a1); b1 = fmaf(v1, bf_hi(x1), b1);
            a2 = fmaf(v2, bf_lo(x2), a2); b2 = fmaf(v2, bf_hi(x2), b2);
            a3 = fmaf(v3, bf_lo(x3), a3); b3 = fmaf(v3, bf_hi(x3), b3);
        }
        for (; i < e; ++i) {
            const int2 c = cv[i];
            const unsigned x = X[(size_t)c.x * LPR + lane];
            const float v = __int_as_float(c.y);
            a0 = fmaf(v, bf_lo(x), a0); b0 = fmaf(v, bf_hi(x), b0);
        }
    }
    float r0 = (a0 + a1) + (a2 + a3);
    float r1 = (b0 + b1) + (b2 + b3);
    if (RELU) { r0 = fmaxf(r0, 0.f); r1 = fmaxf(r1, 0.f); }
    if (YF32) {
        *reinterpret_cast<float2*>((float*)Yv + (size_t)row * HH + lane * 2) = make_float2(r0, r1);
    } else {
        ((unsigned*)Yv)[(size_t)row * LPR + lane] = pack_bf16(r0, r1);
    }
}

extern "C" void kernel_launch(void* const* d_in, const int* in_sizes, int n_in,
                              void* d_out, int out_size, void* d_ws, size_t ws_size,
                              hipStream_t stream) {
    const float* feat0 = (const float*)d_in[0];
    const float* feat1 = (const float*)d_in[1];
    const int*   e00_row = (const int*)d_in[2];
    const int*   e00_col = (const int*)d_in[3];
    const float* e00_val = (const float*)d_in[4];
    const int*   e01_row = (const int*)d_in[5];
    const int*   e01_col = (const int*)d_in[6];
    const float* e01_val = (const float*)d_in[7];
    const int*   e10_row = (const int*)d_in[8];
    const int*   e10_col = (const int*)d_in[9];
    const float* e10_val = (const float*)d_in[10];
    const int*   e11_row = (const int*)d_in[11];
    const int*   e11_col = (const int*)d_in[12];
    const float* e11_val = (const float*)d_in[13];
    const float* W1_00 = (const float*)d_in[14];
    const float* W1_01 = (const float*)d_in[15];
    const float* W1_10 = (const float*)d_in[16];
    const float* W1_11 = (const float*)d_in[17];
    const float* W2_00 = (const float*)d_in[18];
    const float* W2_01 = (const float*)d_in[19];
    const float* W2_10 = (const float*)d_in[20];
    const float* W2_11 = (const float*)d_in[21];

    const int N0  = in_sizes[0] / F;
    const int N1  = in_sizes[1] / F;
    const int E00 = in_sizes[2];
    const int E01 = in_sizes[5];
    const int E10 = in_sizes[8];
    const int E11 = in_sizes[11] / K11;
    const long long E_total = (long long)E00 + E01 + E10 + (long long)K11 * E11;

    // concatenated row-space offsets
    const int s00 = 0, s01 = N0, s10 = 2 * N0, s11 = 2 * N0 + N1;
    const int L = 2 * N0 + (1 + K11) * N1;

    struct HArr { const int* rows; const int* cols; const float* vals; int E; int s; int n; };
    const HArr arrs[6] = {
        {e00_row, e00_col, e00_val, E00, s00, N0},
        {e01_row, e01_col, e01_val, E01, s01, N0},
        {e10_row, e10_col, e10_val, E10, s10, N1},
        {e11_row,           e11_col,           e11_val,           E11, s11,          N1},
        {e11_row + E11,     e11_col + E11,     e11_val + E11,     E11, s11 + N1,     N1},
        {e11_row + 2*E11,   e11_col + 2*E11,   e11_val + 2*E11,   E11, s11 + 2*N1,   N1},
    };

    // ---- common workspace head ----
    ushort* h0 = (ushort*)d_ws;
    ushort* h1 = h0 + (size_t)N0 * H1;
    ushort* g  = h1 + (size_t)N1 * H1;
    const size_t gElems = ((size_t)N0 + (size_t)K11 * N1) * H1;
    int* iw = (int*)(g + gElems);

    int maxE = 0, maxN = 0;
    for (int i = 0; i < 6; ++i) { maxE = max(maxE, arrs[i].E); maxN = max(maxN, arrs[i].n); }
    const bool canPack = (maxN <= 65536) && ((size_t)maxE * 8 <= gElems * 2);

    const int* gptrP = nullptr;
    const int2* cvP = nullptr;

    if (canPack) {
        // ---- new build layout ----
        int nbins_[6], binBase_[6], edgeBase_[6];
        int TB = 0; long long eb = 0;
        for (int i = 0; i < 6; ++i) {
            binBase_[i] = TB; nbins_[i] = (arrs[i].n + 127) >> BSH; TB += nbins_[i];
            edgeBase_[i] = (int)eb; eb += arrs[i].E;
        }
        const int TBc = (TB + 2 + 3) & ~3;
        int* binCnt = iw;
        int* binPtr = binCnt + TBc;          // TB+1 used
        int* binCur = binPtr + TBc;
        int* gptr   = binCur + TBc;          // L+1
        const int Lc = (L + 1 + 3) & ~3;
        int2* cv    = (int2*)(gptr + Lc);
        uint2* tmp  = (uint2*)g;             // aliases GEMM scratch; build precedes GEMMs in-stream

        const size_t required = ((size_t)(N0 + N1) * H1 + gElems) * 2
                              + ((size_t)3 * TBc + Lc + 2 * (size_t)E_total) * 4;
        if (ws_size < required) return;

        hipMemsetAsync(binCnt, 0, (size_t)TBc * sizeof(int), stream);
        BinDesc bd;
        for (int i = 0; i < 6; ++i) { bd.rows[i] = arrs[i].rows; bd.E[i] = arrs[i].E; bd.n[i] = arrs[i].n; bd.binBase[i] = binBase_[i]; }
        binhist_kernel<<<dim3((maxE + 8191) / 8192, 6), 256, 0, stream>>>(bd, binCnt);
        binscan_kernel<<<1, 256, 0, stream>>>(binCnt, binPtr, binCur, TB, (int)E_total, gptr, L);
        for (int i = 0; i < 6; ++i) {
            partition_kernel<<<(arrs[i].E + 4095) / 4096, 256, 0, stream>>>(
                arrs[i].rows, arrs[i].cols, arrs[i].vals, arrs[i].E, nbins_[i],
                binCur + binBase_[i], edgeBase_[i], tmp);
            finalize_kernel<<<nbins_[i], 256, 0, stream>>>(
                tmp, binPtr + binBase_[i], edgeBase_[i], arrs[i].n, gptr + arrs[i].s, cv);
        }
        gptrP = gptr; cvP = cv;
    } else {
        // ---- fallback build (round-5) ----
        const int Lcap = ((L + 1 + 1023) / 1024) * 1024;
        const int nb = Lcap / 1024;
        int* counts = iw;
        int* gptr   = counts + Lcap;
        int* cur    = gptr + Lcap;
        int* bsums  = cur + Lcap;
        int* bofs   = bsums + 256;
        int2* cv    = (int2*)(bofs + 256);
        const size_t required = ((size_t)(N0 + N1) * H1 + gElems) * 2
                              + ((size_t)3 * Lcap + 512 + 2 * (size_t)E_total) * 4;
        if (ws_size < required) return;

        hipMemsetAsync(counts, 0, (size_t)Lcap * sizeof(int), stream);
        hist_kernel<<<(E00 + 255) / 256, 256, 0, stream>>>(e00_row, E00, counts + s00);
        hist_kernel<<<(E01 + 255) / 256, 256, 0, stream>>>(e01_row, E01, counts + s01);
        hist_kernel<<<(E10 + 255) / 256, 256, 0, stream>>>(e10_row, E10, counts + s10);
        hist_k_kernel<<<dim3((E11 + 255) / 256, K11), 256, 0, stream>>>(e11_row, E11, N1, counts + s11);
        scan1_kernel<<<nb, 256, 0, stream>>>(counts, bsums);
        scan2_kernel<<<1, 256, 0, stream>>>(bsums, bofs, nb);
        scan3_kernel<<<nb, 256, 0, stream>>>(counts, bofs, gptr, cur);
        scatter_kernel<<<(E00 + 255) / 256, 256, 0, stream>>>(e00_row, e00_col, e00_val, E00, cur + s00, cv);
        scatter_kernel<<<(E01 + 255) / 256, 256, 0, stream>>>(e01_row, e01_col, e01_val, E01, cur + s01, cv);
        scatter_kernel<<<(E10 + 255) / 256, 256, 0, stream>>>(e10_row, e10_col, e10_val, E10, cur + s10, cv);
        scatter_k_kernel<<<dim3((E11 + 255) / 256, K11), 256, 0, stream>>>(e11_row, e11_col, e11_val, E11, N1, cur + s11, cv);
        gptrP = gptr; cvP = cv;
    }

    // -------- main sequence (round-5 proven) --------
    float* z0 = (float*)d_out;
    float* z1 = (float*)d_out + (size_t)N0 * H2;

    {   // h0 = relu(e00 @ (feat0 W1_00) + e01 @ (feat1 W1_01))
        ushort* gA = g;
        ushort* gB = g + (size_t)N0 * H1;
        gemm_kernel<F, H1, 4, false, false><<<(N0 * 4 + 255) / 256, 256, 0, stream>>>(feat0, W1_00, gA, N0);
        gemm_kernel<F, H1, 4, false, false><<<(N1 * 4 + 255) / 256, 256, 0, stream>>>(feat1, W1_01, gB, N1);
        Segs sg; sg.n = 2;
        sg.off[0] = s00; sg.X[0] = gA;
        sg.off[1] = s01; sg.X[1] = gB;
        spmm_seg_kernel<H1, true, false><<<(N0 + 7) / 8, 256, 0, stream>>>(gptrP, sg, cvP, h0, N0);
    }
    {   // h1 = relu(e10 @ (feat0 W1_10) + sum_k e11_k @ (feat1 W1_11k))
        ushort* gA = g;
        ushort* gB = g + (size_t)N0 * H1;
        gemm_kernel<F, H1, 4, false, false><<<(N0 * 4 + 255) / 256, 256, 0, stream>>>(feat0, W1_10, gA, N0);
        gemm_kernel<F, H1, 4, true, false><<<dim3((N1 * 4 + 255) / 256, K11), 256, 0, stream>>>(feat1, W1_11, gB, N1);
        Segs sg; sg.n = 4;
        sg.off[0] = s10; sg.X[0] = gA;
        for (int k = 0; k < K11; ++k) { sg.off[1 + k] = s11 + k * N1; sg.X[1 + k] = gB + (size_t)k * N1 * H1; }
        spmm_seg_kernel<H1, true, false><<<(N1 + 7) / 8, 256, 0, stream>>>(gptrP, sg, cvP, h1, N1);
    }
    {   // z0 = e00 @ (h0 W2_00) + e01 @ (h1 W2_01)
        ushort* gA = g;
        ushort* gB = g + (size_t)N0 * H2;
        gemm_kernel<H1, H2, 4, false, true><<<(N0 * 4 + 255) / 256, 256, 0, stream>>>(h0, W2_00, gA, N0);
        gemm_kernel<H1, H2, 4, false, true><<<(N1 * 4 + 255) / 256, 256, 0, stream>>>(h1, W2_01, gB, N1);
        Segs sg; sg.n = 2;
        sg.off[0] = s00; sg.X[0] = gA;
        sg.off[1] = s01; sg.X[1] = gB;
        spmm_seg_kernel<H2, false, true><<<(N0 + 15) / 16, 256, 0, stream>>>(gptrP, sg, cvP, z0, N0);
    }
    {   // z1 = e10 @ (h0 W2_10) + sum_k e11_k @ (h1 W2_11k)
        ushort* gA = g;
        ushort* gB = g + (size_t)N0 * H2;
        gemm_kernel<H1, H2, 4, false, true><<<(N0 * 4 + 255) / 256, 256, 0, stream>>>(h0, W2_10, gA, N0);
        gemm_kernel<H1, H2, 4, true, true><<<dim3((N1 * 4 + 255) / 256, K11), 256, 0, stream>>>(h1, W2_11, gB, N1);
        Segs sg; sg.n = 4;
        sg.off[0] = s10; sg.X[0] = gA;
        for (int k = 0; k < K11; ++k) { sg.off[1 + k] = s11 + k * N1; sg.X[1 + k] = gB + (size_t)k * N1 * H2; }
        spmm_seg_kernel<H2, false, true><<<(N1 + 15) / 16, 256, 0, stream>>>(gptrP, sg, cvP, z1, N1);
    }

    (void)n_in; (void)out_size;
}

// Round 7
// 484.735 us; speedup vs baseline: 4.9939x; 1.1241x over previous
//
#include <hip/hip_runtime.h>
#include <hip/hip_bf16.h>

constexpr int F = 128, H1 = 64, H2 = 32, K11 = 3;
constexpr int BSH = 6;                 // 64 rows per bin
constexpr int PARTE = 2048;            // edges per partition block

// ---- bf16 helpers ----
static __device__ __forceinline__ float bf_lo(unsigned u) { return __uint_as_float(u << 16); }
static __device__ __forceinline__ float bf_hi(unsigned u) { return __uint_as_float(u & 0xffff0000u); }
static __device__ __forceinline__ unsigned bf16_1(float a) {     // low-16 bf16 (RNE)
    unsigned ua = __float_as_uint(a);
    return (ua + 0x7fffu + ((ua >> 16) & 1u)) >> 16;
}
static __device__ __forceinline__ unsigned pack_bf16(float a, float b) {
    unsigned ua = __float_as_uint(a), ub = __float_as_uint(b);
    unsigned ra = (ua + 0x7fffu + ((ua >> 16) & 1u)) >> 16;
    unsigned rb = (ub + 0x7fffu + ((ub >> 16) & 1u)) & 0xffff0000u;
    return ra | rb;
}

// ---------------- batched dense GEMM: C_y[M x HH](bf16) = A[M x FF] @ W_y[FF x HH] ----------------
struct GemmB { const float* W[4]; long long cOff[4]; };

template<int FF, int HH, bool ABF16>
__launch_bounds__(256)
__global__ void gemm_b_kernel(const void* __restrict__ Av, GemmB gb,
                              ushort* __restrict__ Cb, int M) {
    const float* __restrict__ W = gb.W[blockIdx.y];
    ushort* C = Cb + gb.cOff[blockIdx.y];
    __shared__ float Ws[FF * HH];
    const int tid = threadIdx.x;
    for (int i = tid * 4; i < FF * HH; i += 1024)
        *reinterpret_cast<float4*>(&Ws[i]) = *reinterpret_cast<const float4*>(&W[i]);
    __syncthreads();

    constexpr int TPR = 4;
    constexpr int CPT = HH / TPR;
    const int t = blockIdx.x * 256 + tid;
    const int row = t / TPR;
    const int sub = t % TPR;
    if (row >= M) return;

    float acc[CPT];
#pragma unroll
    for (int j = 0; j < CPT; ++j) acc[j] = 0.f;

    for (int k = 0; k < FF; k += 8) {
        float av[8];
        if (ABF16) {
            const uint4 u = *reinterpret_cast<const uint4*>((const ushort*)Av + (size_t)row * FF + k);
            av[0] = bf_lo(u.x); av[1] = bf_hi(u.x);
            av[2] = bf_lo(u.y); av[3] = bf_hi(u.y);
            av[4] = bf_lo(u.z); av[5] = bf_hi(u.z);
            av[6] = bf_lo(u.w); av[7] = bf_hi(u.w);
        } else {
            const float* A = (const float*)Av + (size_t)row * FF + k;
            const float4 u0 = *reinterpret_cast<const float4*>(A);
            const float4 u1 = *reinterpret_cast<const float4*>(A + 4);
            av[0] = u0.x; av[1] = u0.y; av[2] = u0.z; av[3] = u0.w;
            av[4] = u1.x; av[5] = u1.y; av[6] = u1.z; av[7] = u1.w;
        }
#pragma unroll
        for (int kk = 0; kk < 8; ++kk) {
            const float* wr = &Ws[(k + kk) * HH + sub * CPT];
#pragma unroll
            for (int j = 0; j < CPT; j += 4) {
                const float4 wv = *reinterpret_cast<const float4*>(&wr[j]);
                acc[j + 0] = fmaf(av[kk], wv.x, acc[j + 0]);
                acc[j + 1] = fmaf(av[kk], wv.y, acc[j + 1]);
                acc[j + 2] = fmaf(av[kk], wv.z, acc[j + 2]);
                acc[j + 3] = fmaf(av[kk], wv.w, acc[j + 3]);
            }
        }
    }
    unsigned packed[CPT / 2];
#pragma unroll
    for (int j = 0; j < CPT; j += 2) packed[j / 2] = pack_bf16(acc[j], acc[j + 1]);
    unsigned* c = (unsigned*)(C + (size_t)row * HH + sub * CPT);
#pragma unroll
    for (int j = 0; j < CPT / 2; j += 4)
        *reinterpret_cast<uint4*>(&c[j]) = make_uint4(packed[j], packed[j + 1], packed[j + 2], packed[j + 3]);
}

// ---------------- CSR build: two-level bin partition (64-row bins) ----------------
struct BinDesc { const int* rows[6]; int E[6]; int n[6]; int binBase[6]; };

__launch_bounds__(256)
__global__ void binhist_kernel(BinDesc d, int* __restrict__ binCnt) {
    const int a = blockIdx.y;
    const int E = d.E[a];
    const int start = blockIdx.x * 8192;
    if (start >= E) return;
    const int nb = (d.n[a] + 63) >> BSH;        // <= 1024
    __shared__ int h[1024];
    for (int i = threadIdx.x; i < nb; i += 256) h[i] = 0;
    __syncthreads();
    const int* rows = d.rows[a];
    const int end = min(E, start + 8192);
    for (int e = start + (int)threadIdx.x; e < end; e += 256)
        atomicAdd(&h[rows[e] >> BSH], 1);
    __syncthreads();
    int* bc = binCnt + d.binBase[a];
    for (int i = threadIdx.x; i < nb; i += 256)
        if (h[i]) atomicAdd(&bc[i], h[i]);
}

__launch_bounds__(256)
__global__ void binscan_kernel(const int* __restrict__ binCnt, int* __restrict__ binPtr,
                               int* __restrict__ binCur, int TB, int Etot,
                               int* __restrict__ gptr, int Lidx) {
    __shared__ int lds[256];
    __shared__ int carry;
    if (threadIdx.x == 0) carry = 0;
    __syncthreads();
    for (int base = 0; base < TB; base += 256) {
        const int i = base + threadIdx.x;
        const int v = (i < TB) ? binCnt[i] : 0;
        lds[threadIdx.x] = v;
        __syncthreads();
        for (int o = 1; o < 256; o <<= 1) {
            int t = (threadIdx.x >= o) ? lds[threadIdx.x - o] : 0;
            __syncthreads();
            lds[threadIdx.x] += t;
            __syncthreads();
        }
        const int c = carry;
        __syncthreads();
        if (i < TB) {
            const int excl = c + lds[threadIdx.x] - v;
            binPtr[i] = excl;
            binCur[i] = excl;
        }
        if (threadIdx.x == 255) carry = c + lds[255];
        __syncthreads();
    }
    if (threadIdx.x == 0) { binPtr[TB] = Etot; gptr[Lidx] = Etot; }
}

struct PartD {
    const int* rows[3]; const int* cols[3]; const float* vals[3];
    int E[3]; int nbins[3]; int binBase[3]; int edgeBase[3];   // edgeBase = tmp base (batch-common)
};

__launch_bounds__(256)
__global__ void partition_all_kernel(PartD d, int* __restrict__ binCur,
                                     uint2* __restrict__ tmp) {
    const int a = blockIdx.y;
    const int E = d.E[a];
    const int start = blockIdx.x * PARTE;
    if (start >= E) return;
    const int nbins = d.nbins[a];
    const int* __restrict__ rows = d.rows[a];
    const int* __restrict__ cols = d.cols[a];
    const float* __restrict__ vals = d.vals[a];
    int* __restrict__ bc = binCur + d.binBase[a];
    const int tmpBase = d.edgeBase[a];
    __shared__ int h[1024];
    __shared__ int base[1024];
    for (int i = threadIdx.x; i < nbins; i += 256) h[i] = 0;
    __syncthreads();
    int r[PARTE / 256];
#pragma unroll
    for (int j = 0; j < PARTE / 256; ++j) {
        const int idx = start + j * 256 + (int)threadIdx.x;
        r[j] = (idx < E) ? rows[idx] : -1;
        if (r[j] >= 0) atomicAdd(&h[r[j] >> BSH], 1);
    }
    __syncthreads();
    for (int i = threadIdx.x; i < nbins; i += 256) {
        const int c = h[i];
        base[i] = c ? atomicAdd(&bc[i], c) : 0;
    }
    __syncthreads();
    for (int i = threadIdx.x; i < nbins; i += 256) h[i] = 0;
    __syncthreads();
#pragma unroll
    for (int j = 0; j < PARTE / 256; ++j) {
        if (r[j] >= 0) {
            const int idx = start + j * 256 + (int)threadIdx.x;
            const int b = r[j] >> BSH;
            const int p = atomicAdd(&h[b], 1);
            tmp[(size_t)(base[b] + p - tmpBase)] =
                make_uint2(((unsigned)(r[j] & 63) << 16) | (unsigned)cols[idx],
                           __float_as_uint(vals[idx]));
        }
    }
}

struct FinD { int binBase[3]; int edgeBase[3]; int n[3]; int rowBase[3]; };

__launch_bounds__(256)
__global__ void finalize_all_kernel(FinD d, const uint2* __restrict__ tmp,
                                    const int* __restrict__ binPtr,
                                    int* __restrict__ gptr, unsigned* __restrict__ cv) {
    const int a = blockIdx.y;
    const int n = d.n[a];
    const int nbins = (n + 63) >> BSH;
    const int b = blockIdx.x;
    if (b >= nbins) return;
    const int* bp = binPtr + d.binBase[a];
    const int binStart = bp[b], binEnd = bp[b + 1];
    const int lo = binStart - d.edgeBase[a], hi = binEnd - d.edgeBase[a];
    __shared__ int cnt[64], off[64], cur[64];
    if (threadIdx.x < 64) cnt[threadIdx.x] = 0;
    __syncthreads();
    for (int i = lo + (int)threadIdx.x; i < hi; i += 256)
        atomicAdd(&cnt[tmp[i].x >> 16], 1);
    __syncthreads();
    if (threadIdx.x < 64) off[threadIdx.x] = cnt[threadIdx.x];
    __syncthreads();
    for (int o = 1; o < 64; o <<= 1) {
        int t = 0;
        if (threadIdx.x < 64 && (int)threadIdx.x >= o) t = off[threadIdx.x - o];
        __syncthreads();
        if (threadIdx.x < 64) off[threadIdx.x] += t;
        __syncthreads();
    }
    const int r0 = b << BSH;
    const int nrows = min(64, n - r0);
    if (threadIdx.x < 64) {
        const int excl = off[threadIdx.x] - cnt[threadIdx.x];
        cur[threadIdx.x] = excl;
        if ((int)threadIdx.x < nrows) (gptr + d.rowBase[a])[r0 + threadIdx.x] = binStart + excl;
    }
    __syncthreads();
    for (int i = lo + (int)threadIdx.x; i < hi; i += 256) {
        const uint2 t = tmp[i];
        const int p = atomicAdd(&cur[t.x >> 16], 1);
        cv[binStart + p] = ((t.x & 0xffffu) << 16) | bf16_1(__uint_as_float(t.y));
    }
}

// ---------------- SpMM v2: wave-per-row, EPW edges in parallel, fused 2-part output ----------------
struct SpmmD {
    int n0, nseg0, nseg1;
    int off0[2], off1[4];
    const ushort* X0[2];
    const ushort* X1[4];
};

template<int HH, bool RELU, bool YF32>
__launch_bounds__(256)
__global__ void spmm2_kernel(const int* __restrict__ gptr, SpmmD d,
                             const unsigned* __restrict__ cv,
                             void* __restrict__ Y0, void* __restrict__ Y1,
                             int totalRows) {
    constexpr int LPR = HH / 2;        // unsigneds (bf16 pairs) per row
    constexpr int EPW = 64 / LPR;      // edges in parallel per wave
    const int wid = (int)threadIdx.x >> 6;
    const int lane = (int)threadIdx.x & 63;
    const int sub = lane / LPR;
    const int c = lane % LPR;
    const int grow = blockIdx.x * 4 + wid;
    if (grow >= totalRows) return;

    int row, nseg; void* Y;
    int o[4]; const unsigned* X[4];
    if (grow < d.n0) {
        row = grow; Y = Y0; nseg = d.nseg0;
        o[0] = d.off0[0]; o[1] = d.off0[1]; o[2] = 0; o[3] = 0;
        X[0] = (const unsigned*)d.X0[0]; X[1] = (const unsigned*)d.X0[1];
        X[2] = nullptr; X[3] = nullptr;
    } else {
        row = grow - d.n0; Y = Y1; nseg = d.nseg1;
        o[0] = d.off1[0]; o[1] = d.off1[1]; o[2] = d.off1[2]; o[3] = d.off1[3];
        X[0] = (const unsigned*)d.X1[0]; X[1] = (const unsigned*)d.X1[1];
        X[2] = (const unsigned*)d.X1[2]; X[3] = (const unsigned*)d.X1[3];
    }

    float a[4] = {0.f, 0.f, 0.f, 0.f}, b[4] = {0.f, 0.f, 0.f, 0.f};
#pragma unroll
    for (int sg = 0; sg < 4; ++sg) {
        if (sg < nseg) {
            const int* p = gptr + o[sg] + row;
            const int s = p[0], e = p[1];
            const unsigned* __restrict__ Xs = X[sg];
            int i = s;
            for (; i + 4 * EPW <= e; i += 4 * EPW) {
#pragma unroll
                for (int j = 0; j < 4; ++j) {
                    const unsigned cw = cv[i + j * EPW + sub];
                    const unsigned x = Xs[(size_t)(cw >> 16) * LPR + c];
                    const float v = __uint_as_float(cw << 16);
                    a[j] = fmaf(v, bf_lo(x), a[j]);
                    b[j] = fmaf(v, bf_hi(x), b[j]);
                }
            }
#pragma unroll
            for (int j = 0; j < 4; ++j) {
                const int idx = i + j * EPW + sub;
                if (idx < e) {
                    const unsigned cw = cv[idx];
                    const unsigned x = Xs[(size_t)(cw >> 16) * LPR + c];
                    const float v = __uint_as_float(cw << 16);
                    a[j] = fmaf(v, bf_lo(x), a[j]);
                    b[j] = fmaf(v, bf_hi(x), b[j]);
                }
            }
        }
    }
    float r0 = (a[0] + a[1]) + (a[2] + a[3]);
    float r1 = (b[0] + b[1]) + (b[2] + b[3]);
#pragma unroll
    for (int off = LPR; off < 64; off <<= 1) {
        r0 += __shfl_xor(r0, off, 64);
        r1 += __shfl_xor(r1, off, 64);
    }
    if (sub == 0) {
        if (RELU) { r0 = fmaxf(r0, 0.f); r1 = fmaxf(r1, 0.f); }
        if (YF32) {
            *reinterpret_cast<float2*>((float*)Y + (size_t)row * HH + c * 2) = make_float2(r0, r1);
        } else {
            ((unsigned*)Y)[(size_t)row * LPR + c] = pack_bf16(r0, r1);
        }
    }
}

extern "C" void kernel_launch(void* const* d_in, const int* in_sizes, int n_in,
                              void* d_out, int out_size, void* d_ws, size_t ws_size,
                              hipStream_t stream) {
    const float* feat0 = (const float*)d_in[0];
    const float* feat1 = (const float*)d_in[1];
    const int*   e00_row = (const int*)d_in[2];
    const int*   e00_col = (const int*)d_in[3];
    const float* e00_val = (const float*)d_in[4];
    const int*   e01_row = (const int*)d_in[5];
    const int*   e01_col = (const int*)d_in[6];
    const float* e01_val = (const float*)d_in[7];
    const int*   e10_row = (const int*)d_in[8];
    const int*   e10_col = (const int*)d_in[9];
    const float* e10_val = (const float*)d_in[10];
    const int*   e11_row = (const int*)d_in[11];
    const int*   e11_col = (const int*)d_in[12];
    const float* e11_val = (const float*)d_in[13];
    const float* W1_00 = (const float*)d_in[14];
    const float* W1_01 = (const float*)d_in[15];
    const float* W1_10 = (const float*)d_in[16];
    const float* W1_11 = (const float*)d_in[17];
    const float* W2_00 = (const float*)d_in[18];
    const float* W2_01 = (const float*)d_in[19];
    const float* W2_10 = (const float*)d_in[20];
    const float* W2_11 = (const float*)d_in[21];

    const int N0  = in_sizes[0] / F;
    const int N1  = in_sizes[1] / F;
    const int E00 = in_sizes[2];
    const int E01 = in_sizes[5];
    const int E10 = in_sizes[8];
    const int E11 = in_sizes[11] / K11;
    const long long E_total = (long long)E00 + E01 + E10 + (long long)K11 * E11;

    const int s00 = 0, s01 = N0, s10 = 2 * N0, s11 = 2 * N0 + N1;
    const int L = 2 * N0 + (1 + K11) * N1;

    struct HA { const int* rows; const int* cols; const float* vals; int E; int s; int n; };
    const HA arrs[6] = {
        {e00_row, e00_col, e00_val, E00, s00, N0},
        {e01_row, e01_col, e01_val, E01, s01, N0},
        {e10_row, e10_col, e10_val, E10, s10, N1},
        {e11_row,          e11_col,          e11_val,          E11, s11,          N1},
        {e11_row + E11,    e11_col + E11,    e11_val + E11,    E11, s11 + N1,     N1},
        {e11_row + 2*E11,  e11_col + 2*E11,  e11_val + 2*E11,  E11, s11 + 2*N1,   N1},
    };

    int nbins_[6], binBase_[6]; long long edgeBase_[6];
    int TB = 0; long long eb = 0;
    int maxE = 0;
    for (int i = 0; i < 6; ++i) {
        binBase_[i] = TB; nbins_[i] = (arrs[i].n + 63) >> BSH; TB += nbins_[i];
        edgeBase_[i] = eb; eb += arrs[i].E;
        maxE = max(maxE, arrs[i].E);
    }
    const int TBc = (TB + 2 + 3) & ~3;
    const int Lc = (L + 1 + 3) & ~3;

    // ---- workspace layout ----
    ushort* h0 = (ushort*)d_ws;                       // N0*H1 bf16
    ushort* h1 = h0 + (size_t)N0 * H1;                // N1*H1 bf16
    ushort* g  = h1 + (size_t)N1 * H1;                // (2N0+4N1)*H1 bf16 stage buffer (aliased by tmp)
    const size_t G = ((size_t)2 * N0 + 4 * N1) * H1;
    int* iw = (int*)(g + G);
    int* binCnt = iw;
    int* binPtr = binCnt + TBc;
    int* binCur = binPtr + TBc;
    int* gptr   = binCur + TBc;
    unsigned* cv = (unsigned*)(gptr + Lc);

    const size_t required = ((size_t)(N0 + N1) * H1 + G) * 2
                          + ((size_t)3 * TBc + Lc + (size_t)E_total) * 4;
    const size_t trioBytes = (size_t)K11 * E11 * 8;
    if (ws_size < required || N0 > 65536 || N1 > 65536 ||
        (size_t)maxE * 8 > G * 2 || trioBytes > G * 2) return;

    // -------- CSR build --------
    hipMemsetAsync(binCnt, 0, (size_t)TBc * sizeof(int), stream);
    BinDesc bd;
    for (int i = 0; i < 6; ++i) { bd.rows[i] = arrs[i].rows; bd.E[i] = arrs[i].E; bd.n[i] = arrs[i].n; bd.binBase[i] = binBase_[i]; }
    binhist_kernel<<<dim3((maxE + 8191) / 8192, 6), 256, 0, stream>>>(bd, binCnt);
    binscan_kernel<<<1, 256, 0, stream>>>(binCnt, binPtr, binCur, TB, (int)E_total, gptr, L);

    uint2* tmp = (uint2*)g;
    auto launchPF = [&](int first, int cnt) {
        const long long tmpBase = edgeBase_[first];
        PartD pd{}; FinD fd{};
        int mE = 0, mNB = 0;
        for (int j = 0; j < cnt; ++j) {
            const int i = first + j;
            pd.rows[j] = arrs[i].rows; pd.cols[j] = arrs[i].cols; pd.vals[j] = arrs[i].vals;
            pd.E[j] = arrs[i].E; pd.nbins[j] = nbins_[i]; pd.binBase[j] = binBase_[i];
            pd.edgeBase[j] = (int)tmpBase;
            fd.binBase[j] = binBase_[i]; fd.edgeBase[j] = (int)tmpBase;
            fd.n[j] = arrs[i].n; fd.rowBase[j] = arrs[i].s;
            mE = max(mE, arrs[i].E); mNB = max(mNB, nbins_[i]);
        }
        partition_all_kernel<<<dim3((mE + PARTE - 1) / PARTE, cnt), 256, 0, stream>>>(pd, binCur, tmp);
        finalize_all_kernel<<<dim3(mNB, cnt), 256, 0, stream>>>(fd, tmp, binPtr, gptr, cv);
    };
    launchPF(0, 1);
    launchPF(1, 1);
    launchPF(2, 1);
    launchPF(3, 3);

    // -------- main sequence --------
    float* z0 = (float*)d_out;
    float* z1 = (float*)d_out + (size_t)N0 * H2;
    const int TR = N0 + N1;

    // layer 1 GEMMs: g rows = [A(N0) | B(N1) | C(N0) | D0(N1) D1(N1) D2(N1)]
    {
        GemmB ga; ga.W[0] = W1_00; ga.cOff[0] = 0;
        ga.W[1] = W1_10; ga.cOff[1] = (long long)(N0 + N1) * H1;
        ga.W[2] = W1_00; ga.cOff[2] = 0; ga.W[3] = W1_00; ga.cOff[3] = 0;
        gemm_b_kernel<F, H1, false><<<dim3((N0 * 4 + 255) / 256, 2), 256, 0, stream>>>(feat0, ga, g, N0);
        GemmB gbt; gbt.W[0] = W1_01; gbt.cOff[0] = (long long)N0 * H1;
        for (int k = 0; k < K11; ++k) {
            gbt.W[1 + k] = W1_11 + (size_t)k * F * H1;
            gbt.cOff[1 + k] = ((long long)(2 * N0 + N1) + (long long)k * N1) * H1;
        }
        gemm_b_kernel<F, H1, false><<<dim3((N1 * 4 + 255) / 256, 4), 256, 0, stream>>>(feat1, gbt, g, N1);
    }
    // layer 1 SpMM (h0 + h1 fused)
    {
        SpmmD sd;
        sd.n0 = N0; sd.nseg0 = 2; sd.nseg1 = 4;
        sd.off0[0] = s00; sd.X0[0] = g;
        sd.off0[1] = s01; sd.X0[1] = g + (size_t)N0 * H1;
        sd.off1[0] = s10; sd.X1[0] = g + (size_t)(N0 + N1) * H1;
        for (int k = 0; k < K11; ++k) {
            sd.off1[1 + k] = s11 + k * N1;
            sd.X1[1 + k] = g + ((size_t)(2 * N0 + N1) + (size_t)k * N1) * H1;
        }
        spmm2_kernel<H1, true, false><<<(TR + 3) / 4, 256, 0, stream>>>(gptr, sd, cv, h0, h1, TR);
    }
    // layer 2 GEMMs (A = h0 / h1, bf16)
    {
        GemmB ga; ga.W[0] = W2_00; ga.cOff[0] = 0;
        ga.W[1] = W2_10; ga.cOff[1] = (long long)(N0 + N1) * H2;
        ga.W[2] = W2_00; ga.cOff[2] = 0; ga.W[3] = W2_00; ga.cOff[3] = 0;
        gemm_b_kernel<H1, H2, true><<<dim3((N0 * 4 + 255) / 256, 2), 256, 0, stream>>>(h0, ga, g, N0);
        GemmB gbt; gbt.W[0] = W2_01; gbt.cOff[0] = (long long)N0 * H2;
        for (int k = 0; k < K11; ++k) {
            gbt.W[1 + k] = W2_11 + (size_t)k * H1 * H2;
            gbt.cOff[1 + k] = ((long long)(2 * N0 + N1) + (long long)k * N1) * H2;
        }
        gemm_b_kernel<H1, H2, true><<<dim3((N1 * 4 + 255) / 256, 4), 256, 0, stream>>>(h1, gbt, g, N1);
    }
    // layer 2 SpMM (z0 + z1 fused, f32 out)
    {
        SpmmD sd;
        sd.n0 = N0; sd.nseg0 = 2; sd.nseg1 = 4;
        sd.off0[0] = s00; sd.X0[0] = g;
        sd.off0[1] = s01; sd.X0[1] = g + (size_t)N0 * H2;
        sd.off1[0] = s10; sd.X1[0] = g + (size_t)(N0 + N1) * H2;
        for (int k = 0; k < K11; ++k) {
            sd.off1[1 + k] = s11 + k * N1;
            sd.X1[1 + k] = g + ((size_t)(2 * N0 + N1) + (size_t)k * N1) * H2;
        }
        spmm2_kernel<H2, false, true><<<(TR + 3) / 4, 256, 0, stream>>>(gptr, sd, cv, z0, z1, TR);
    }

    (void)n_in; (void)out_size;
}

// Round 8
// 421.938 us; speedup vs baseline: 5.7372x; 1.1488x over previous
//
#include <hip/hip_runtime.h>
#include <hip/hip_bf16.h>

constexpr int F = 128, H1 = 64, H2 = 32, K11 = 3;
constexpr int BSH = 6;                 // 64 rows per bin
constexpr int PARTE = 2048;            // edges per partition block

// ---- bf16 helpers ----
static __device__ __forceinline__ float bf_lo(unsigned u) { return __uint_as_float(u << 16); }
static __device__ __forceinline__ float bf_hi(unsigned u) { return __uint_as_float(u & 0xffff0000u); }
static __device__ __forceinline__ unsigned bf16_1(float a) {     // low-16 bf16 (RNE)
    unsigned ua = __float_as_uint(a);
    return (ua + 0x7fffu + ((ua >> 16) & 1u)) >> 16;
}
static __device__ __forceinline__ unsigned pack_bf16(float a, float b) {
    unsigned ua = __float_as_uint(a), ub = __float_as_uint(b);
    unsigned ra = (ua + 0x7fffu + ((ua >> 16) & 1u)) >> 16;
    unsigned rb = (ub + 0x7fffu + ((ub >> 16) & 1u)) & 0xffff0000u;
    return ra | rb;
}

// ---------------- batched dense GEMM: C_y[M x HH](bf16) = A[M x FF] @ W_y[FF x HH] ----------------
struct GemmB { const float* W[4]; long long cOff[4]; };

template<int FF, int HH, bool ABF16>
__launch_bounds__(256)
__global__ void gemm_b_kernel(const void* __restrict__ Av, GemmB gb,
                              ushort* __restrict__ Cb, int M) {
    const float* __restrict__ W = gb.W[blockIdx.y];
    ushort* C = Cb + gb.cOff[blockIdx.y];
    __shared__ float Ws[FF * HH];
    const int tid = threadIdx.x;
    for (int i = tid * 4; i < FF * HH; i += 1024)
        *reinterpret_cast<float4*>(&Ws[i]) = *reinterpret_cast<const float4*>(&W[i]);
    __syncthreads();

    constexpr int TPR = 4;
    constexpr int CPT = HH / TPR;
    const int t = blockIdx.x * 256 + tid;
    const int row = t / TPR;
    const int sub = t % TPR;
    if (row >= M) return;

    float acc[CPT];
#pragma unroll
    for (int j = 0; j < CPT; ++j) acc[j] = 0.f;

    for (int k = 0; k < FF; k += 8) {
        float av[8];
        if (ABF16) {
            const uint4 u = *reinterpret_cast<const uint4*>((const ushort*)Av + (size_t)row * FF + k);
            av[0] = bf_lo(u.x); av[1] = bf_hi(u.x);
            av[2] = bf_lo(u.y); av[3] = bf_hi(u.y);
            av[4] = bf_lo(u.z); av[5] = bf_hi(u.z);
            av[6] = bf_lo(u.w); av[7] = bf_hi(u.w);
        } else {
            const float* A = (const float*)Av + (size_t)row * FF + k;
            const float4 u0 = *reinterpret_cast<const float4*>(A);
            const float4 u1 = *reinterpret_cast<const float4*>(A + 4);
            av[0] = u0.x; av[1] = u0.y; av[2] = u0.z; av[3] = u0.w;
            av[4] = u1.x; av[5] = u1.y; av[6] = u1.z; av[7] = u1.w;
        }
#pragma unroll
        for (int kk = 0; kk < 8; ++kk) {
            const float* wr = &Ws[(k + kk) * HH + sub * CPT];
#pragma unroll
            for (int j = 0; j < CPT; j += 4) {
                const float4 wv = *reinterpret_cast<const float4*>(&wr[j]);
                acc[j + 0] = fmaf(av[kk], wv.x, acc[j + 0]);
                acc[j + 1] = fmaf(av[kk], wv.y, acc[j + 1]);
                acc[j + 2] = fmaf(av[kk], wv.z, acc[j + 2]);
                acc[j + 3] = fmaf(av[kk], wv.w, acc[j + 3]);
            }
        }
    }
    unsigned packed[CPT / 2];
#pragma unroll
    for (int j = 0; j < CPT; j += 2) packed[j / 2] = pack_bf16(acc[j], acc[j + 1]);
    unsigned* c = (unsigned*)(C + (size_t)row * HH + sub * CPT);
#pragma unroll
    for (int j = 0; j < CPT / 2; j += 4)
        *reinterpret_cast<uint4*>(&c[j]) = make_uint4(packed[j], packed[j + 1], packed[j + 2], packed[j + 3]);
}

// ---------------- CSR build: two-level bin partition (64-row bins) ----------------
struct BinDesc { const int* rows[6]; int E[6]; int n[6]; int binBase[6]; };

__launch_bounds__(256)
__global__ void binhist_kernel(BinDesc d, int* __restrict__ binCnt) {
    const int a = blockIdx.y;
    const int E = d.E[a];
    const int start = blockIdx.x * 8192;
    if (start >= E) return;
    const int nb = (d.n[a] + 63) >> BSH;        // <= 1024
    __shared__ int h[1024];
    for (int i = threadIdx.x; i < nb; i += 256) h[i] = 0;
    __syncthreads();
    const int* rows = d.rows[a];
    const int end = min(E, start + 8192);
    for (int e = start + (int)threadIdx.x; e < end; e += 256)
        atomicAdd(&h[rows[e] >> BSH], 1);
    __syncthreads();
    int* bc = binCnt + d.binBase[a];
    for (int i = threadIdx.x; i < nb; i += 256)
        if (h[i]) atomicAdd(&bc[i], h[i]);
}

__launch_bounds__(256)
__global__ void binscan_kernel(const int* __restrict__ binCnt, int* __restrict__ binPtr,
                               int* __restrict__ binCur, int TB, int Etot,
                               int* __restrict__ gptr, int Lidx) {
    __shared__ int lds[256];
    __shared__ int carry;
    if (threadIdx.x == 0) carry = 0;
    __syncthreads();
    for (int base = 0; base < TB; base += 256) {
        const int i = base + threadIdx.x;
        const int v = (i < TB) ? binCnt[i] : 0;
        lds[threadIdx.x] = v;
        __syncthreads();
        for (int o = 1; o < 256; o <<= 1) {
            int t = (threadIdx.x >= o) ? lds[threadIdx.x - o] : 0;
            __syncthreads();
            lds[threadIdx.x] += t;
            __syncthreads();
        }
        const int c = carry;
        __syncthreads();
        if (i < TB) {
            const int excl = c + lds[threadIdx.x] - v;
            binPtr[i] = excl;
            binCur[i] = excl;
        }
        if (threadIdx.x == 255) carry = c + lds[255];
        __syncthreads();
    }
    if (threadIdx.x == 0) { binPtr[TB] = Etot; gptr[Lidx] = Etot; }
}

struct PartD {
    const int* rows[4]; const int* cols[4]; const float* vals[4];
    int E[4]; int nbins[4]; int binBase[4]; int edgeBase[4];
};

__launch_bounds__(256)
__global__ void partition_all_kernel(PartD d, int* __restrict__ binCur,
                                     uint2* __restrict__ tmp) {
    const int a = blockIdx.y;
    const int E = d.E[a];
    const int start = blockIdx.x * PARTE;
    if (start >= E) return;
    const int nbins = d.nbins[a];
    const int* __restrict__ rows = d.rows[a];
    const int* __restrict__ cols = d.cols[a];
    const float* __restrict__ vals = d.vals[a];
    int* __restrict__ bc = binCur + d.binBase[a];
    const int tmpBase = d.edgeBase[a];
    __shared__ int h[1024];
    __shared__ int base[1024];
    for (int i = threadIdx.x; i < nbins; i += 256) h[i] = 0;
    __syncthreads();
    int r[PARTE / 256];
#pragma unroll
    for (int j = 0; j < PARTE / 256; ++j) {
        const int idx = start + j * 256 + (int)threadIdx.x;
        r[j] = (idx < E) ? rows[idx] : -1;
        if (r[j] >= 0) atomicAdd(&h[r[j] >> BSH], 1);
    }
    __syncthreads();
    for (int i = threadIdx.x; i < nbins; i += 256) {
        const int c = h[i];
        base[i] = c ? atomicAdd(&bc[i], c) : 0;
    }
    __syncthreads();
    for (int i = threadIdx.x; i < nbins; i += 256) h[i] = 0;
    __syncthreads();
#pragma unroll
    for (int j = 0; j < PARTE / 256; ++j) {
        if (r[j] >= 0) {
            const int idx = start + j * 256 + (int)threadIdx.x;
            const int b = r[j] >> BSH;
            const int p = atomicAdd(&h[b], 1);
            tmp[(size_t)(base[b] + p - tmpBase)] =
                make_uint2(((unsigned)(r[j] & 63) << 16) | (unsigned)cols[idx],
                           __float_as_uint(vals[idx]));
        }
    }
}

struct FinD { int binBase[4]; int edgeBase[4]; int n[4]; int rowBase[4]; };

__launch_bounds__(256)
__global__ void finalize_all_kernel(FinD d, const uint2* __restrict__ tmp,
                                    const int* __restrict__ binPtr,
                                    int* __restrict__ gptr, unsigned* __restrict__ cv) {
    const int a = blockIdx.y;
    const int n = d.n[a];
    const int nbins = (n + 63) >> BSH;
    const int b = blockIdx.x;
    if (b >= nbins) return;
    const int* bp = binPtr + d.binBase[a];
    const int binStart = bp[b], binEnd = bp[b + 1];
    const int lo = binStart - d.edgeBase[a], hi = binEnd - d.edgeBase[a];
    __shared__ int cnt[64], off[64], cur[64];
    if (threadIdx.x < 64) cnt[threadIdx.x] = 0;
    __syncthreads();
    for (int i = lo + (int)threadIdx.x; i < hi; i += 256)
        atomicAdd(&cnt[tmp[i].x >> 16], 1);
    __syncthreads();
    if (threadIdx.x < 64) off[threadIdx.x] = cnt[threadIdx.x];
    __syncthreads();
    for (int o = 1; o < 64; o <<= 1) {
        int t = 0;
        if (threadIdx.x < 64 && (int)threadIdx.x >= o) t = off[threadIdx.x - o];
        __syncthreads();
        if (threadIdx.x < 64) off[threadIdx.x] += t;
        __syncthreads();
    }
    const int r0 = b << BSH;
    const int nrows = min(64, n - r0);
    if (threadIdx.x < 64) {
        const int excl = off[threadIdx.x] - cnt[threadIdx.x];
        cur[threadIdx.x] = excl;
        if ((int)threadIdx.x < nrows) (gptr + d.rowBase[a])[r0 + threadIdx.x] = binStart + excl;
    }
    __syncthreads();
    for (int i = lo + (int)threadIdx.x; i < hi; i += 256) {
        const uint2 t = tmp[i];
        const int p = atomicAdd(&cur[t.x >> 16], 1);
        cv[binStart + p] = ((t.x & 0xffffu) << 16) | bf16_1(__uint_as_float(t.y));
    }
}

// ---------------- SpMM v3: wave-per-row, 8B gathers, EPW edges in parallel ----------------
struct SpmmD {
    int n0, nseg0, nseg1;
    int off0[2], off1[4];
    const ushort* X0[2];
    const ushort* X1[4];
};

template<int HH, bool RELU, bool YF32>
__launch_bounds__(256)
__global__ void spmm2_kernel(const int* __restrict__ gptr, SpmmD d,
                             const unsigned* __restrict__ cv,
                             void* __restrict__ Y0, void* __restrict__ Y1,
                             int totalRows) {
    constexpr int LPR = HH / 4;        // lanes per row (uint2 = 4 bf16 each)
    constexpr int EPW = 64 / LPR;      // edges in parallel per wave (H1: 4, H2: 8)
    const int wid = (int)threadIdx.x >> 6;
    const int lane = (int)threadIdx.x & 63;
    const int sub = lane / LPR;        // edge slot
    const int c = lane % LPR;          // uint2 index within row
    const int grow = blockIdx.x * 4 + wid;
    if (grow >= totalRows) return;

    int row, nseg; void* Y;
    int o[4]; const uint2* X[4];
    if (grow < d.n0) {
        row = grow; Y = Y0; nseg = d.nseg0;
        o[0] = d.off0[0]; o[1] = d.off0[1]; o[2] = 0; o[3] = 0;
        X[0] = (const uint2*)d.X0[0]; X[1] = (const uint2*)d.X0[1];
        X[2] = nullptr; X[3] = nullptr;
    } else {
        row = grow - d.n0; Y = Y1; nseg = d.nseg1;
        o[0] = d.off1[0]; o[1] = d.off1[1]; o[2] = d.off1[2]; o[3] = d.off1[3];
        X[0] = (const uint2*)d.X1[0]; X[1] = (const uint2*)d.X1[1];
        X[2] = (const uint2*)d.X1[2]; X[3] = (const uint2*)d.X1[3];
    }

    float4 a0 = {0,0,0,0}, a1 = {0,0,0,0}, a2 = {0,0,0,0}, a3 = {0,0,0,0};
#pragma unroll
    for (int sg = 0; sg < 4; ++sg) {
        if (sg < nseg) {
            const int* p = gptr + o[sg] + row;
            const int s = p[0], e = p[1];
            const uint2* __restrict__ Xs = X[sg];
            int i = s;
            for (; i + 4 * EPW <= e; i += 4 * EPW) {
                const unsigned cw0 = cv[i + 0 * EPW + sub];
                const unsigned cw1 = cv[i + 1 * EPW + sub];
                const unsigned cw2 = cv[i + 2 * EPW + sub];
                const unsigned cw3 = cv[i + 3 * EPW + sub];
                const uint2 x0 = Xs[(size_t)(cw0 >> 16) * LPR + c];
                const uint2 x1 = Xs[(size_t)(cw1 >> 16) * LPR + c];
                const uint2 x2 = Xs[(size_t)(cw2 >> 16) * LPR + c];
                const uint2 x3 = Xs[(size_t)(cw3 >> 16) * LPR + c];
                const float v0 = __uint_as_float(cw0 << 16);
                const float v1 = __uint_as_float(cw1 << 16);
                const float v2 = __uint_as_float(cw2 << 16);
                const float v3 = __uint_as_float(cw3 << 16);
                a0.x = fmaf(v0, bf_lo(x0.x), a0.x); a0.y = fmaf(v0, bf_hi(x0.x), a0.y);
                a0.z = fmaf(v0, bf_lo(x0.y), a0.z); a0.w = fmaf(v0, bf_hi(x0.y), a0.w);
                a1.x = fmaf(v1, bf_lo(x1.x), a1.x); a1.y = fmaf(v1, bf_hi(x1.x), a1.y);
                a1.z = fmaf(v1, bf_lo(x1.y), a1.z); a1.w = fmaf(v1, bf_hi(x1.y), a1.w);
                a2.x = fmaf(v2, bf_lo(x2.x), a2.x); a2.y = fmaf(v2, bf_hi(x2.x), a2.y);
                a2.z = fmaf(v2, bf_lo(x2.y), a2.z); a2.w = fmaf(v2, bf_hi(x2.y), a2.w);
                a3.x = fmaf(v3, bf_lo(x3.x), a3.x); a3.y = fmaf(v3, bf_hi(x3.x), a3.y);
                a3.z = fmaf(v3, bf_lo(x3.y), a3.z); a3.w = fmaf(v3, bf_hi(x3.y), a3.w);
            }
#pragma unroll
            for (int j = 0; j < 4; ++j) {
                const int idx = i + j * EPW + sub;
                if (idx < e) {
                    const unsigned cw = cv[idx];
                    const uint2 x = Xs[(size_t)(cw >> 16) * LPR + c];
                    const float v = __uint_as_float(cw << 16);
                    a0.x = fmaf(v, bf_lo(x.x), a0.x); a0.y = fmaf(v, bf_hi(x.x), a0.y);
                    a0.z = fmaf(v, bf_lo(x.y), a0.z); a0.w = fmaf(v, bf_hi(x.y), a0.w);
                }
            }
        }
    }
    float4 r;
    r.x = (a0.x + a1.x) + (a2.x + a3.x);
    r.y = (a0.y + a1.y) + (a2.y + a3.y);
    r.z = (a0.z + a1.z) + (a2.z + a3.z);
    r.w = (a0.w + a1.w) + (a2.w + a3.w);
#pragma unroll
    for (int off = LPR; off < 64; off <<= 1) {
        r.x += __shfl_xor(r.x, off, 64);
        r.y += __shfl_xor(r.y, off, 64);
        r.z += __shfl_xor(r.z, off, 64);
        r.w += __shfl_xor(r.w, off, 64);
    }
    if (sub == 0) {
        if (RELU) {
            r.x = fmaxf(r.x, 0.f); r.y = fmaxf(r.y, 0.f);
            r.z = fmaxf(r.z, 0.f); r.w = fmaxf(r.w, 0.f);
        }
        if (YF32) {
            *reinterpret_cast<float4*>((float*)Y + (size_t)row * HH + c * 4) = r;
        } else {
            reinterpret_cast<uint2*>((unsigned*)Y + (size_t)row * (HH / 2))[c] =
                make_uint2(pack_bf16(r.x, r.y), pack_bf16(r.z, r.w));
        }
    }
}

extern "C" void kernel_launch(void* const* d_in, const int* in_sizes, int n_in,
                              void* d_out, int out_size, void* d_ws, size_t ws_size,
                              hipStream_t stream) {
    const float* feat0 = (const float*)d_in[0];
    const float* feat1 = (const float*)d_in[1];
    const int*   e00_row = (const int*)d_in[2];
    const int*   e00_col = (const int*)d_in[3];
    const float* e00_val = (const float*)d_in[4];
    const int*   e01_row = (const int*)d_in[5];
    const int*   e01_col = (const int*)d_in[6];
    const float* e01_val = (const float*)d_in[7];
    const int*   e10_row = (const int*)d_in[8];
    const int*   e10_col = (const int*)d_in[9];
    const float* e10_val = (const float*)d_in[10];
    const int*   e11_row = (const int*)d_in[11];
    const int*   e11_col = (const int*)d_in[12];
    const float* e11_val = (const float*)d_in[13];
    const float* W1_00 = (const float*)d_in[14];
    const float* W1_01 = (const float*)d_in[15];
    const float* W1_10 = (const float*)d_in[16];
    const float* W1_11 = (const float*)d_in[17];
    const float* W2_00 = (const float*)d_in[18];
    const float* W2_01 = (const float*)d_in[19];
    const float* W2_10 = (const float*)d_in[20];
    const float* W2_11 = (const float*)d_in[21];

    const int N0  = in_sizes[0] / F;
    const int N1  = in_sizes[1] / F;
    const int E00 = in_sizes[2];
    const int E01 = in_sizes[5];
    const int E10 = in_sizes[8];
    const int E11 = in_sizes[11] / K11;
    const long long E_total = (long long)E00 + E01 + E10 + (long long)K11 * E11;

    const int s00 = 0, s01 = N0, s10 = 2 * N0, s11 = 2 * N0 + N1;
    const int L = 2 * N0 + (1 + K11) * N1;

    struct HA { const int* rows; const int* cols; const float* vals; int E; int s; int n; };
    const HA arrs[6] = {
        {e00_row, e00_col, e00_val, E00, s00, N0},
        {e01_row, e01_col, e01_val, E01, s01, N0},
        {e10_row, e10_col, e10_val, E10, s10, N1},
        {e11_row,          e11_col,          e11_val,          E11, s11,          N1},
        {e11_row + E11,    e11_col + E11,    e11_val + E11,    E11, s11 + N1,     N1},
        {e11_row + 2*E11,  e11_col + 2*E11,  e11_val + 2*E11,  E11, s11 + 2*N1,   N1},
    };

    int nbins_[6], binBase_[6]; long long edgeBase_[6];
    int TB = 0; long long eb = 0;
    int maxE = 0;
    for (int i = 0; i < 6; ++i) {
        binBase_[i] = TB; nbins_[i] = (arrs[i].n + 63) >> BSH; TB += nbins_[i];
        edgeBase_[i] = eb; eb += arrs[i].E;
        maxE = max(maxE, arrs[i].E);
    }
    const int TBc = (TB + 2 + 3) & ~3;
    const int Lc = (L + 1 + 3) & ~3;

    // ---- workspace layout ----
    ushort* h0 = (ushort*)d_ws;                       // N0*H1 bf16
    ushort* h1 = h0 + (size_t)N0 * H1;                // N1*H1 bf16
    ushort* g  = h1 + (size_t)N1 * H1;                // (2N0+4N1)*H1 bf16 stage buffer (aliased by tmp)
    const size_t G = ((size_t)2 * N0 + 4 * N1) * H1;
    int* iw = (int*)(g + G);
    int* binCnt = iw;
    int* binPtr = binCnt + TBc;
    int* binCur = binPtr + TBc;
    int* gptr   = binCur + TBc;
    unsigned* cv = (unsigned*)(gptr + Lc);

    const size_t required = ((size_t)(N0 + N1) * H1 + G) * 2
                          + ((size_t)3 * TBc + Lc + (size_t)E_total) * 4;
    const size_t batchA = ((size_t)E00 + E01) * 8;
    const size_t batchB = ((size_t)E10 + (size_t)K11 * E11) * 8;
    if (ws_size < required || N0 > 65536 || N1 > 65536 ||
        batchA > G * 2 || batchB > G * 2) return;

    // -------- CSR build --------
    hipMemsetAsync(binCnt, 0, (size_t)TBc * sizeof(int), stream);
    BinDesc bd;
    for (int i = 0; i < 6; ++i) { bd.rows[i] = arrs[i].rows; bd.E[i] = arrs[i].E; bd.n[i] = arrs[i].n; bd.binBase[i] = binBase_[i]; }
    binhist_kernel<<<dim3((maxE + 8191) / 8192, 6), 256, 0, stream>>>(bd, binCnt);
    binscan_kernel<<<1, 256, 0, stream>>>(binCnt, binPtr, binCur, TB, (int)E_total, gptr, L);

    uint2* tmp = (uint2*)g;
    auto launchPF = [&](int first, int cnt) {
        const long long tmpBase = edgeBase_[first];
        PartD pd{}; FinD fd{};
        int mE = 0, mNB = 0;
        for (int j = 0; j < cnt; ++j) {
            const int i = first + j;
            pd.rows[j] = arrs[i].rows; pd.cols[j] = arrs[i].cols; pd.vals[j] = arrs[i].vals;
            pd.E[j] = arrs[i].E; pd.nbins[j] = nbins_[i]; pd.binBase[j] = binBase_[i];
            pd.edgeBase[j] = (int)tmpBase;
            fd.binBase[j] = binBase_[i]; fd.edgeBase[j] = (int)tmpBase;
            fd.n[j] = arrs[i].n; fd.rowBase[j] = arrs[i].s;
            mE = max(mE, arrs[i].E); mNB = max(mNB, nbins_[i]);
        }
        partition_all_kernel<<<dim3((mE + PARTE - 1) / PARTE, cnt), 256, 0, stream>>>(pd, binCur, tmp);
        finalize_all_kernel<<<dim3(mNB, cnt), 256, 0, stream>>>(fd, tmp, binPtr, gptr, cv);
    };
    launchPF(0, 2);   // e00 + e01
    launchPF(2, 4);   // e10 + e11 x3

    // -------- main sequence --------
    float* z0 = (float*)d_out;
    float* z1 = (float*)d_out + (size_t)N0 * H2;
    const int TR = N0 + N1;

    // layer 1 GEMMs: g rows = [A(N0) | B(N1) | C(N0) | D0(N1) D1(N1) D2(N1)]
    {
        GemmB ga; ga.W[0] = W1_00; ga.cOff[0] = 0;
        ga.W[1] = W1_10; ga.cOff[1] = (long long)(N0 + N1) * H1;
        ga.W[2] = W1_00; ga.cOff[2] = 0; ga.W[3] = W1_00; ga.cOff[3] = 0;
        gemm_b_kernel<F, H1, false><<<dim3((N0 * 4 + 255) / 256, 2), 256, 0, stream>>>(feat0, ga, g, N0);
        GemmB gbt; gbt.W[0] = W1_01; gbt.cOff[0] = (long long)N0 * H1;
        for (int k = 0; k < K11; ++k) {
            gbt.W[1 + k] = W1_11 + (size_t)k * F * H1;
            gbt.cOff[1 + k] = ((long long)(2 * N0 + N1) + (long long)k * N1) * H1;
        }
        gemm_b_kernel<F, H1, false><<<dim3((N1 * 4 + 255) / 256, 4), 256, 0, stream>>>(feat1, gbt, g, N1);
    }
    // layer 1 SpMM (h0 + h1 fused)
    {
        SpmmD sd;
        sd.n0 = N0; sd.nseg0 = 2; sd.nseg1 = 4;
        sd.off0[0] = s00; sd.X0[0] = g;
        sd.off0[1] = s01; sd.X0[1] = g + (size_t)N0 * H1;
        sd.off1[0] = s10; sd.X1[0] = g + (size_t)(N0 + N1) * H1;
        for (int k = 0; k < K11; ++k) {
            sd.off1[1 + k] = s11 + k * N1;
            sd.X1[1 + k] = g + ((size_t)(2 * N0 + N1) + (size_t)k * N1) * H1;
        }
        spmm2_kernel<H1, true, false><<<(TR + 3) / 4, 256, 0, stream>>>(gptr, sd, cv, h0, h1, TR);
    }
    // layer 2 GEMMs (A = h0 / h1, bf16)
    {
        GemmB ga; ga.W[0] = W2_00; ga.cOff[0] = 0;
        ga.W[1] = W2_10; ga.cOff[1] = (long long)(N0 + N1) * H2;
        ga.W[2] = W2_00; ga.cOff[2] = 0; ga.W[3] = W2_00; ga.cOff[3] = 0;
        gemm_b_kernel<H1, H2, true><<<dim3((N0 * 4 + 255) / 256, 2), 256, 0, stream>>>(h0, ga, g, N0);
        GemmB gbt; gbt.W[0] = W2_01; gbt.cOff[0] = (long long)N0 * H2;
        for (int k = 0; k < K11; ++k) {
            gbt.W[1 + k] = W2_11 + (size_t)k * H1 * H2;
            gbt.cOff[1 + k] = ((long long)(2 * N0 + N1) + (long long)k * N1) * H2;
        }
        gemm_b_kernel<H1, H2, true><<<dim3((N1 * 4 + 255) / 256, 4), 256, 0, stream>>>(h1, gbt, g, N1);
    }
    // layer 2 SpMM (z0 + z1 fused, f32 out)
    {
        SpmmD sd;
        sd.n0 = N0; sd.nseg0 = 2; sd.nseg1 = 4;
        sd.off0[0] = s00; sd.X0[0] = g;
        sd.off0[1] = s01; sd.X0[1] = g + (size_t)N0 * H2;
        sd.off1[0] = s10; sd.X1[0] = g + (size_t)(N0 + N1) * H2;
        for (int k = 0; k < K11; ++k) {
            sd.off1[1 + k] = s11 + k * N1;
            sd.X1[1 + k] = g + ((size_t)(2 * N0 + N1) + (size_t)k * N1) * H2;
        }
        spmm2_kernel<H2, false, true><<<(TR + 3) / 4, 256, 0, stream>>>(gptr, sd, cv, z0, z1, TR);
    }

    (void)n_in; (void)out_size;
}